// Round 13
// baseline (721.411 us; speedup 1.0000x reference)
//
#include <hip/hip_runtime.h>
#include <stdint.h>

#define NN 50000
#define NE 800000
#define NG 512
#define H  128
#define NBUK 391   // ceil(NN/128)

typedef __attribute__((ext_vector_type(8))) short short8;
typedef __attribute__((ext_vector_type(16))) float f32x16;

union U4S8 { uint4 u; short8 s; };

__device__ __forceinline__ float softplusf(float x){
    return fmaxf(x, 0.f) + log1pf(expf(-fabsf(x)));
}

// round-to-nearest-even bf16 bits (high 16) of x
__device__ __forceinline__ unsigned rne_bf16_hi(float x){
    unsigned u = __float_as_uint(x);
    unsigned r = u + 0x7fffu + ((u >> 16) & 1u);
    return r & 0xffff0000u;
}

// split two fp32 into bf16-hi dword and bf16-lo dword (RNE split; residual ~2^-17)
__device__ __forceinline__ void split_pack(float x0, float x1, unsigned &hi, unsigned &lo){
    unsigned h0 = rne_bf16_hi(x0), h1 = rne_bf16_hi(x1);
    hi = (h0 >> 16) | h1;
    float l0 = x0 - __uint_as_float(h0);
    float l1 = x1 - __uint_as_float(h1);
    unsigned g0 = rne_bf16_hi(l0), g1 = rne_bf16_hi(l1);
    lo = (g0 >> 16) | g1;
}

// pack adjacent-lane pair into one bf16x2 dword; even lanes store
__device__ __forceinline__ void store_xb_pair(unsigned* __restrict__ xbu, int mm,
                                              int cp, int c31, int lane, float v0, float v1){
    float p0 = __shfl_xor(v0, 1);
    float p1 = __shfl_xor(v1, 1);
    if (!(lane & 1)){
        unsigned u0 = (rne_bf16_hi(v0) >> 16) | (rne_bf16_hi(p0) & 0xffff0000u);
        unsigned u1 = (rne_bf16_hi(v1) >> 16) | (rne_bf16_hi(p1) & 0xffff0000u);
        xbu[(size_t)mm*64 + 32*cp      + (c31>>1)] = u0;
        xbu[(size_t)mm*64 + 32*cp + 16 + (c31>>1)] = u1;
    }
}

// ---------------- sentinel writer ----------------
__global__ void k_sentinel(float* out, float val){
    int i = blockIdx.x*256 + threadIdx.x;
    if (i < 6*NG) out[i] = val;
}

// ---------------- GIN W pre-split into MFMA B-fragment order ----------------
__global__ __launch_bounds__(64) void k_wsplit(const float* __restrict__ gW1,
    const float* __restrict__ gW2, uint4* __restrict__ wf)
{
    int bid = blockIdx.x, lane = threadIdx.x;
    int mat = bid >> 5, ntg = (bid >> 3) & 3, ks = bid & 7;
    int l = mat >> 1;
    const float* W = (mat & 1) ? (gW2 + (size_t)l*H*H) : (gW1 + (size_t)l*H*H);
    int n  = ntg*32 + (lane & 31);
    int kb = ks*16 + (lane >> 5)*8;
    unsigned hi[4], lo[4];
#pragma unroll
    for (int d=0; d<4; d++){
        float x0 = W[(size_t)(kb + 2*d    )*H + n];
        float x1 = W[(size_t)(kb + 2*d + 1)*H + n];
        split_pack(x0, x1, hi[d], lo[d]);
    }
    int bh = ((mat*2 + 0)*4 + ntg)*8 + ks;
    int bl = ((mat*2 + 1)*4 + ntg)*8 + ks;
    wf[bh*64 + lane] = make_uint4(hi[0],hi[1],hi[2],hi[3]);
    wf[bl*64 + lane] = make_uint4(lo[0],lo[1],lo[2],lo[3]);
}

// ---------------- W_comb (256x128) pre-split ----------------
__global__ __launch_bounds__(64) void k_wsplit_embed(const float* __restrict__ Wc,
    uint4* __restrict__ wcf)
{
    int bid = blockIdx.x, lane = threadIdx.x;
    int ntg = bid >> 4, ks = bid & 15;
    int n  = ntg*32 + (lane & 31);
    int kb = ks*16 + (lane >> 5)*8;
    unsigned hi[4], lo[4];
#pragma unroll
    for (int d=0; d<4; d++){
        float x0 = Wc[(size_t)(kb + 2*d    )*H + n];
        float x1 = Wc[(size_t)(kb + 2*d + 1)*H + n];
        split_pack(x0, x1, hi[d], lo[d]);
    }
    wcf[((0*4 + ntg)*16 + ks)*64 + lane] = make_uint4(hi[0],hi[1],hi[2],hi[3]);
    wcf[((1*4 + ntg)*16 + ks)*64 + lane] = make_uint4(lo[0],lo[1],lo[2],lo[3]);
}

// ---------------- initial embedding via MFMA ----------------
__global__ __launch_bounds__(256) void k_embed_mfma(const int* __restrict__ z,
    const float* __restrict__ pos, const float* __restrict__ emb,
    const float* __restrict__ Wp, const float* __restrict__ bp,
    const float* __restrict__ bc, const uint4* __restrict__ wcf,
    float* __restrict__ xout, unsigned* __restrict__ xbu)
{
    __shared__ unsigned short AhiF[2*8*64*8];
    __shared__ unsigned short AloF[2*8*64*8];
    const int t = threadIdx.x, lane = t & 63, w = t >> 6;
    const int rt = w & 1, cp = w >> 1;
    const int mb = blockIdx.x * 64;
    const int c31 = lane & 31;
    const int q = lane >> 5;

    const int r = t >> 2, c4 = t & 3;
    const int gr = mb + r;
    const int gre = (gr < NN) ? gr : (NN-1);
    const int zr = z[gre];
    const float p0 = pos[gre*3+0], p1 = pos[gre*3+1], p2 = pos[gre*3+2];
    const int rt_s = r >> 5, r31s = r & 31;

    f32x16 acc0, acc1;
#pragma unroll
    for (int i=0;i<16;i++){ acc0[i]=0.f; acc1[i]=0.f; }

#pragma unroll
    for (int kh2=0; kh2<2; kh2++){
        if (kh2) __syncthreads();
#pragma unroll
        for (int i=0;i<8;i++){
            int cl = c4*4 + i*16;
            float4 v;
            if (kh2 == 0){
                v = *(const float4*)(emb + (size_t)zr*H + cl);
            } else {
                float4 w0 = *(const float4*)(Wp + cl);
                float4 w1 = *(const float4*)(Wp + H + cl);
                float4 w2 = *(const float4*)(Wp + 2*H + cl);
                float4 bb = *(const float4*)(bp + cl);
                v.x = p0*w0.x + p1*w1.x + p2*w2.x + bb.x;
                v.y = p0*w0.y + p1*w1.y + p2*w2.y + bb.y;
                v.z = p0*w0.z + p1*w1.z + p2*w2.z + bb.z;
                v.w = p0*w0.w + p1*w1.w + p2*w2.w + bb.w;
            }
            unsigned h0,l0,h1,l1;
            split_pack(v.x, v.y, h0, l0);
            split_pack(v.z, v.w, h1, l1);
            int idx = ((rt_s*8 + (cl>>4))*64 + ((cl>>3)&1)*32 + r31s)*8 + (cl & 7);
            *(uint2*)&AhiF[idx] = make_uint2(h0, h1);
            *(uint2*)&AloF[idx] = make_uint2(l0, l1);
        }
        __syncthreads();
#pragma unroll
        for (int ks=0; ks<8; ks++){
            int ksg = kh2*8 + ks;
            U4S8 ah, al, bh0, bl0, bh1, bl1;
            ah.u  = *(const uint4*)&AhiF[((rt*8+ks)*64 + lane)*8];
            al.u  = *(const uint4*)&AloF[((rt*8+ks)*64 + lane)*8];
            bh0.u = wcf[((0*4 + 2*cp+0)*16 + ksg)*64 + lane];
            bl0.u = wcf[((1*4 + 2*cp+0)*16 + ksg)*64 + lane];
            bh1.u = wcf[((0*4 + 2*cp+1)*16 + ksg)*64 + lane];
            bl1.u = wcf[((1*4 + 2*cp+1)*16 + ksg)*64 + lane];
            acc0 = __builtin_amdgcn_mfma_f32_32x32x16_bf16(ah.s, bh0.s, acc0, 0,0,0);
            acc0 = __builtin_amdgcn_mfma_f32_32x32x16_bf16(ah.s, bl0.s, acc0, 0,0,0);
            acc0 = __builtin_amdgcn_mfma_f32_32x32x16_bf16(al.s, bh0.s, acc0, 0,0,0);
            acc1 = __builtin_amdgcn_mfma_f32_32x32x16_bf16(ah.s, bh1.s, acc1, 0,0,0);
            acc1 = __builtin_amdgcn_mfma_f32_32x32x16_bf16(ah.s, bl1.s, acc1, 0,0,0);
            acc1 = __builtin_amdgcn_mfma_f32_32x32x16_bf16(al.s, bh1.s, acc1, 0,0,0);
        }
    }

    const float bva = bc[64*cp + c31], bvb = bc[64*cp + 32 + c31];
#pragma unroll
    for (int reg=0; reg<16; reg++){
        int row = 32*rt + (reg & 3) + 8*(reg >> 2) + 4*q;
        int mm = mb + row;
        if (mm < NN){
            float v0 = fmaxf(acc0[reg] + bva, 0.f);
            float v1 = fmaxf(acc1[reg] + bvb, 0.f);
            xout[(size_t)mm*H + 64*cp      + c31] = v0;
            xout[(size_t)mm*H + 64*cp + 32 + c31] = v1;
            store_xb_pair(xbu, mm, cp, c31, lane, v0, v1);
        }
    }
}

// ---------------- fused GIN MLP: LDS-staged bf16x2-split MFMA ----------------
__global__ __launch_bounds__(256) void k_gin_mfma(const float* __restrict__ hx,
    const float* __restrict__ b1, const float* __restrict__ b2,
    const uint4* __restrict__ wf, float* __restrict__ xout,
    unsigned* __restrict__ xbu, int l, int relu2)
{
    __shared__ unsigned short AhiF[2*8*64*8];
    __shared__ unsigned short AloF[2*8*64*8];
    const int t = threadIdx.x, lane = t & 63, w = t >> 6;
    const int rt = w & 1, cp = w >> 1;
    const int mb = blockIdx.x * 64;
    const int c31 = lane & 31;
    const int q = lane >> 5;

    {
        int r = t >> 2, c4 = t & 3;
        int gr = mb + r;
        const float* rowp = hx + (size_t)((gr < NN) ? gr : (NN-1))*H;
        int rt_s = r >> 5, r31 = r & 31;
#pragma unroll
        for (int i=0;i<8;i++){
            int col = c4*4 + i*16;
            float4 v = *(const float4*)(rowp + col);
            unsigned h0,l0,h1,l1;
            split_pack(v.x, v.y, h0, l0);
            split_pack(v.z, v.w, h1, l1);
            int idx = ((rt_s*8 + i)*64 + ((col>>3)&1)*32 + r31)*8 + (col & 7);
            *(uint2*)&AhiF[idx] = make_uint2(h0, h1);
            *(uint2*)&AloF[idx] = make_uint2(l0, l1);
        }
    }
    __syncthreads();

    const float bv1a = b1[64*cp + c31], bv1b = b1[64*cp + 32 + c31];
    const float bv2a = b2[64*cp + c31], bv2b = b2[64*cp + 32 + c31];
    const int mat1 = l*2, mat2 = l*2 + 1;

    f32x16 acc0, acc1;
#pragma unroll
    for (int i=0;i<16;i++){ acc0[i]=0.f; acc1[i]=0.f; }

#pragma unroll
    for (int ks=0; ks<8; ks++){
        U4S8 ah, al, bh0, bl0, bh1, bl1;
        ah.u  = *(const uint4*)&AhiF[((rt*8+ks)*64 + lane)*8];
        al.u  = *(const uint4*)&AloF[((rt*8+ks)*64 + lane)*8];
        bh0.u = wf[(((mat1*2+0)*4 + 2*cp+0)*8 + ks)*64 + lane];
        bl0.u = wf[(((mat1*2+1)*4 + 2*cp+0)*8 + ks)*64 + lane];
        bh1.u = wf[(((mat1*2+0)*4 + 2*cp+1)*8 + ks)*64 + lane];
        bl1.u = wf[(((mat1*2+1)*4 + 2*cp+1)*8 + ks)*64 + lane];
        acc0 = __builtin_amdgcn_mfma_f32_32x32x16_bf16(ah.s, bh0.s, acc0, 0,0,0);
        acc0 = __builtin_amdgcn_mfma_f32_32x32x16_bf16(ah.s, bl0.s, acc0, 0,0,0);
        acc0 = __builtin_amdgcn_mfma_f32_32x32x16_bf16(al.s, bh0.s, acc0, 0,0,0);
        acc1 = __builtin_amdgcn_mfma_f32_32x32x16_bf16(ah.s, bh1.s, acc1, 0,0,0);
        acc1 = __builtin_amdgcn_mfma_f32_32x32x16_bf16(ah.s, bl1.s, acc1, 0,0,0);
        acc1 = __builtin_amdgcn_mfma_f32_32x32x16_bf16(al.s, bh1.s, acc1, 0,0,0);
    }

    __syncthreads();
#pragma unroll
    for (int reg=0; reg<16; reg++){
        int r31o = (reg & 3) + 8*(reg >> 2) + 4*q;
        float v0 = fmaxf(acc0[reg] + bv1a, 0.f);
        float v1 = fmaxf(acc1[reg] + bv1b, 0.f);
        {
            int k = 64*cp + c31;
            int idx = ((rt*8 + (k>>4))*64 + ((k>>3)&1)*32 + r31o)*8 + (k & 7);
            unsigned hb = rne_bf16_hi(v0);
            AhiF[idx] = (unsigned short)(hb >> 16);
            AloF[idx] = (unsigned short)(rne_bf16_hi(v0 - __uint_as_float(hb)) >> 16);
        }
        {
            int k = 64*cp + 32 + c31;
            int idx = ((rt*8 + (k>>4))*64 + ((k>>3)&1)*32 + r31o)*8 + (k & 7);
            unsigned hb = rne_bf16_hi(v1);
            AhiF[idx] = (unsigned short)(hb >> 16);
            AloF[idx] = (unsigned short)(rne_bf16_hi(v1 - __uint_as_float(hb)) >> 16);
        }
    }
    __syncthreads();

#pragma unroll
    for (int i=0;i<16;i++){ acc0[i]=0.f; acc1[i]=0.f; }
#pragma unroll
    for (int ks=0; ks<8; ks++){
        U4S8 ah, al, bh0, bl0, bh1, bl1;
        ah.u  = *(const uint4*)&AhiF[((rt*8+ks)*64 + lane)*8];
        al.u  = *(const uint4*)&AloF[((rt*8+ks)*64 + lane)*8];
        bh0.u = wf[(((mat2*2+0)*4 + 2*cp+0)*8 + ks)*64 + lane];
        bl0.u = wf[(((mat2*2+1)*4 + 2*cp+0)*8 + ks)*64 + lane];
        bh1.u = wf[(((mat2*2+0)*4 + 2*cp+1)*8 + ks)*64 + lane];
        bl1.u = wf[(((mat2*2+1)*4 + 2*cp+1)*8 + ks)*64 + lane];
        acc0 = __builtin_amdgcn_mfma_f32_32x32x16_bf16(ah.s, bh0.s, acc0, 0,0,0);
        acc0 = __builtin_amdgcn_mfma_f32_32x32x16_bf16(ah.s, bl0.s, acc0, 0,0,0);
        acc0 = __builtin_amdgcn_mfma_f32_32x32x16_bf16(al.s, bh0.s, acc0, 0,0,0);
        acc1 = __builtin_amdgcn_mfma_f32_32x32x16_bf16(ah.s, bh1.s, acc1, 0,0,0);
        acc1 = __builtin_amdgcn_mfma_f32_32x32x16_bf16(ah.s, bl1.s, acc1, 0,0,0);
        acc1 = __builtin_amdgcn_mfma_f32_32x32x16_bf16(al.s, bh1.s, acc1, 0,0,0);
    }

#pragma unroll
    for (int reg=0; reg<16; reg++){
        int row = 32*rt + (reg & 3) + 8*(reg >> 2) + 4*q;
        int mm = mb + row;
        if (mm < NN){
            float v0 = acc0[reg] + bv2a;
            float v1 = acc1[reg] + bv2b;
            if (relu2){ v0 = fmaxf(v0, 0.f); v1 = fmaxf(v1, 0.f); }
            xout[(size_t)mm*H + 64*cp      + c31] = v0;
            xout[(size_t)mm*H + 64*cp + 32 + c31] = v1;
            store_xb_pair(xbu, mm, cp, c31, lane, v0, v1);
        }
    }
}

// ---------------- CSR build: count + scan (unchanged) ----------------
__global__ void k_zero(int* p, int n){ int i=blockIdx.x*256+threadIdx.x; if(i<n) p[i]=0; }

__global__ void k_count(const int* __restrict__ ei, int* __restrict__ cnt){
    int e = blockIdx.x*256+threadIdx.x;
    if (e < NE){ int d = ei[NE+e]; if ((unsigned)d < NN) atomicAdd(&cnt[d], 1); }
}

__global__ __launch_bounds__(256) void k_scan1(const int* __restrict__ cnt,
    int* __restrict__ iptr, int* __restrict__ bsum)
{
    __shared__ int s[256];
    int t = threadIdx.x, i = blockIdx.x*256 + t;
    int v = (i < NN) ? cnt[i] : 0;
    s[t] = v;
    for (int off=1; off<256; off<<=1){
        __syncthreads();
        int tv = (t >= off) ? s[t-off] : 0;
        __syncthreads();
        s[t] += tv;
    }
    __syncthreads();
    if (i < NN) iptr[i] = s[t] - v;
    if (t == 255) bsum[blockIdx.x] = s[255];
}

__global__ void k_scan2(int* bsum, int* iptr, int nb){
    if (threadIdx.x==0 && blockIdx.x==0){
        int run = 0;
        for (int b=0;b<nb;b++){ int v=bsum[b]; bsum[b]=run; run+=v; }
        iptr[NN] = run;
    }
}

__global__ void k_scan3(int* __restrict__ iptr, const int* __restrict__ bsum,
                        int* __restrict__ cur)
{
    int i = blockIdx.x*256 + threadIdx.x;
    if (i < NN){ int v = iptr[i] + bsum[i>>8]; iptr[i]=v; cur[i]=v; }
}

// ---------------- bucketed scatter: phase A (init cursors) ----------------
__global__ void k_bcur(const int* __restrict__ iptr, int* __restrict__ bcur){
    int b = blockIdx.x*256 + threadIdx.x;
    if (b < NBUK) bcur[b] = iptr[b*128];
}

// phase B: append (src,dst) to per-bucket regions (contiguous writes)
__global__ void k_bucket(const int* __restrict__ ei, int* __restrict__ bcur,
                         uint2* __restrict__ tmp)
{
    int e = blockIdx.x*256 + threadIdx.x;
    if (e < NE){
        int srcv = ei[e], d = ei[NE+e];
        if ((unsigned)d < NN){
            int b = d >> 7;
            int p = atomicAdd(&bcur[b], 1);
            tmp[p] = make_uint2((unsigned)srcv, (unsigned)d);
        }
    }
}

// phase C: within-bucket LDS count+scan+place -> sequential esrc writes
__global__ __launch_bounds__(256) void k_place(const int* __restrict__ iptr,
    const uint2* __restrict__ tmp, int* __restrict__ esrc)
{
    __shared__ int cnt[128], sc[128];
    int b = blockIdx.x, t = threadIdx.x;
    int nb = b*128;
    int nn = min(128, NN - nb);
    int s0 = iptr[nb], e0 = iptr[nb + nn];
    if (t < 128) cnt[t] = 0;
    __syncthreads();
    for (int i = s0 + t; i < e0; i += 256)
        atomicAdd(&cnt[tmp[i].y - nb], 1);
    __syncthreads();
    if (t < 128) sc[t] = cnt[t];
    for (int off=1; off<128; off<<=1){
        __syncthreads();
        int v = (t < 128 && t >= off) ? sc[t-off] : 0;
        __syncthreads();
        if (t < 128) sc[t] += v;
    }
    __syncthreads();
    if (t < 128) cnt[t] = sc[t] - cnt[t];   // exclusive prefix -> cursor
    __syncthreads();
    for (int i = s0 + t; i < e0; i += 256){
        uint2 u = tmp[i];
        int p = atomicAdd(&cnt[u.y - nb], 1);
        esrc[s0 + p] = (int)u.x;
    }
}

// ---------------- GIN aggregation: wave-per-node, bf16 gather, 8-deep ----------------
__global__ __launch_bounds__(256) void k_agg(const float* __restrict__ x,
    const unsigned* __restrict__ xbu,
    const int* __restrict__ iptr, const int* __restrict__ esrc, float* __restrict__ h)
{
    int node = blockIdx.x*4 + (threadIdx.x >> 6);
    int lane = threadIdx.x & 63;
    int s = __builtin_amdgcn_readfirstlane(iptr[node]);
    int e = __builtin_amdgcn_readfirstlane(iptr[node+1]);
    const float2* __restrict__ xp = (const float2*)x;
    float2 acc = xp[(size_t)node*64 + lane];
    float2 accb = make_float2(0.f, 0.f);
    int j = s;
#define BF2X(u) __uint_as_float((u) << 16)
#define BF2Y(u) __uint_as_float((u) & 0xffff0000u)
    for (; j+8 <= e; j += 8){
        int i0 = esrc[j+0], i1 = esrc[j+1], i2 = esrc[j+2], i3 = esrc[j+3];
        int i4 = esrc[j+4], i5 = esrc[j+5], i6 = esrc[j+6], i7 = esrc[j+7];
        unsigned u0 = xbu[(size_t)i0*64 + lane];
        unsigned u1 = xbu[(size_t)i1*64 + lane];
        unsigned u2 = xbu[(size_t)i2*64 + lane];
        unsigned u3 = xbu[(size_t)i3*64 + lane];
        unsigned u4 = xbu[(size_t)i4*64 + lane];
        unsigned u5 = xbu[(size_t)i5*64 + lane];
        unsigned u6 = xbu[(size_t)i6*64 + lane];
        unsigned u7 = xbu[(size_t)i7*64 + lane];
        acc.x  += (BF2X(u0) + BF2X(u1)) + (BF2X(u2) + BF2X(u3));
        acc.y  += (BF2Y(u0) + BF2Y(u1)) + (BF2Y(u2) + BF2Y(u3));
        accb.x += (BF2X(u4) + BF2X(u5)) + (BF2X(u6) + BF2X(u7));
        accb.y += (BF2Y(u4) + BF2Y(u5)) + (BF2Y(u6) + BF2Y(u7));
    }
    for (; j < e; j++){
        unsigned u = xbu[(size_t)esrc[j]*64 + lane];
        acc.x += BF2X(u); acc.y += BF2Y(u);
    }
#undef BF2X
#undef BF2Y
    acc.x += accb.x; acc.y += accb.y;
    ((float2*)h)[(size_t)node*64 + lane] = acc;
}

// ---------------- per-graph sum pooling ----------------
__global__ __launch_bounds__(128) void k_pool(const float* __restrict__ x,
    const int* __restrict__ batch, float* __restrict__ aggr)
{
    int g = blockIdx.x, c = threadIdx.x;
    int lo=0, hi=NN;
    while (lo<hi){ int mid=(lo+hi)>>1; if (batch[mid] < g) lo=mid+1; else hi=mid; }
    int s0 = lo;
    hi = NN;
    while (lo<hi){ int mid=(lo+hi)>>1; if (batch[mid] < g+1) lo=mid+1; else hi=mid; }
    int e0 = lo;
    float a0=0.f, a1=0.f, a2=0.f, a3=0.f;
    int i = s0;
    for (; i+4 <= e0; i += 4){
        a0 += x[(size_t)(i+0)*H + c];
        a1 += x[(size_t)(i+1)*H + c];
        a2 += x[(size_t)(i+2)*H + c];
        a3 += x[(size_t)(i+3)*H + c];
    }
    for (; i < e0; i++) a0 += x[(size_t)i*H + c];
    aggr[g*H + c] = (a0+a1) + (a2+a3);
}

// ---------------- heads: per-(graph,head) dot kernel ----------------
// grid = NG*4; b>>2 = graph, b&3 = head.  128 threads; aggr row in LDS.
__global__ __launch_bounds__(128) void k_head_dot(const float* __restrict__ aggr,
    const float* __restrict__ W1, const float* __restrict__ b1,
    const float* __restrict__ W2, float* __restrict__ ok)
{
    __shared__ float a[H];
    __shared__ float red[H];
    int b = blockIdx.x, g = b >> 2, k = b & 3;
    int c = threadIdx.x;
    a[c] = aggr[g*H + c];
    __syncthreads();
    float acc = b1[k*H + c];
    const float* wp = W1 + (size_t)k*H*H + c;
#pragma unroll 8
    for (int q=0; q<H; q++) acc += a[q] * wp[(size_t)q*H];
    red[c] = fmaxf(acc, 0.f) * W2[k*H + c];
    __syncthreads();
    for (int sd=64; sd>0; sd>>=1){
        if (c < sd) red[c] += red[c+sd];
        __syncthreads();
    }
    if (c == 0) ok[b] = red[0];
}

// ---------------- evidential epilogue ----------------
__global__ void k_evid(const float* __restrict__ ok, const float* __restrict__ b2,
                       float* __restrict__ out)
{
    int g = blockIdx.x*256 + threadIdx.x;
    if (g >= NG) return;
    float o0 = ok[g*4+0] + b2[0];
    float o1 = ok[g*4+1] + b2[1];
    float o2 = ok[g*4+2] + b2[2];
    float o3 = ok[g*4+3] + b2[3];
    float alpha = fmaxf(softplusf(o0) + 1.f, 1.f + 1e-4f);
    float beta  = softplusf(o1);
    float nu    = softplusf(o2);
    float am1   = alpha - 1.f;
    float aleat = beta / am1;
    float epis  = beta / (am1 * nu);
    out[0*NG+g] = o3;
    out[1*NG+g] = aleat;
    out[2*NG+g] = epis;
    out[3*NG+g] = nu;
    out[4*NG+g] = alpha;
    out[5*NG+g] = beta;
}

extern "C" void kernel_launch(void* const* d_in, const int* in_sizes, int n_in,
                              void* d_out, int out_size, void* d_ws, size_t ws_size,
                              hipStream_t stream)
{
    const int*   z     = (const int*)d_in[0];
    const float* pos   = (const float*)d_in[1];
    const int*   batch = (const int*)d_in[2];
    const int*   eidx  = (const int*)d_in[3];
    const float* emb   = (const float*)d_in[4];
    const float* Wp    = (const float*)d_in[5];
    const float* bp    = (const float*)d_in[6];
    const float* Wc    = (const float*)d_in[7];
    const float* bc    = (const float*)d_in[8];
    const float* gW1   = (const float*)d_in[9];
    const float* gb1   = (const float*)d_in[10];
    const float* gW2   = (const float*)d_in[11];
    const float* gb2   = (const float*)d_in[12];
    const float* hW1   = (const float*)d_in[13];
    const float* hb1   = (const float*)d_in[14];
    const float* hW2   = (const float*)d_in[15];
    const float* hb2   = (const float*)d_in[16];
    float* out = (float*)d_out;

    bool ok_sizes = (n_in == 17)
        && in_sizes[0] == NN && in_sizes[1] == NN*3 && in_sizes[2] == NN
        && in_sizes[3] == 2*NE && in_sizes[4] == 100*H
        && in_sizes[7] == 2*H*H && in_sizes[9] == 4*H*H
        && in_sizes[13] == 4*H*H && in_sizes[16] == 4;
    if (!ok_sizes){ k_sentinel<<<12, 256, 0, stream>>>(out, 600000.0f); return; }

    const size_t OFF_X    = 256;        // 25,600,000
    const size_t OFF_H    = 25600256;   // 25,600,000 (reused as uint2 tmp pre-loop)
    const size_t OFF_XB   = 51200256;   // 12,800,000
    const size_t OFF_AGGR = 64000256;   // 262,144
    const size_t OFF_IPTR = 64262400;   // 200,004
    const size_t OFF_CUR  = 64462464;   // 200,000
    const size_t OFF_ESRC = 64662464;   // 3,200,000
    const size_t OFF_BSUM = 67862464;   // 784
    const size_t OFF_WF   = 67863296;   // 524,288
    const size_t OFF_WCF  = 68387584;   // 131,072
    const size_t OFF_OK   = 68518656;   // 8,192
    const size_t OFF_BCUR = 68526848;   // 2,048
    const size_t REQ      = 68528896;
    if (ws_size < REQ){ k_sentinel<<<12, 256, 0, stream>>>(out, 500000.0f); return; }

    char* ws = (char*)d_ws;
    float*    x    = (float*)(ws + OFF_X);
    float*    h    = (float*)(ws + OFF_H);
    uint2*    tmp  = (uint2*)(ws + OFF_H);     // alias: dead before layer loop
    unsigned* xb   = (unsigned*)(ws + OFF_XB);
    float*    aggr = (float*)(ws + OFF_AGGR);
    int*      iptr = (int*)(ws + OFF_IPTR);
    int*      cur  = (int*)(ws + OFF_CUR);
    int*      esrc = (int*)(ws + OFF_ESRC);
    int*      bsum = (int*)(ws + OFF_BSUM);
    uint4*    wf   = (uint4*)(ws + OFF_WF);
    uint4*    wcf  = (uint4*)(ws + OFF_WCF);
    float*    ok   = (float*)(ws + OFF_OK);
    int*      bcur = (int*)(ws + OFF_BCUR);

    k_wsplit_embed<<<64, 64, 0, stream>>>(Wc, wcf);
    k_embed_mfma<<<(NN+63)/64, 256, 0, stream>>>(z, pos, emb, Wp, bp, bc, wcf, x, xb);

    k_wsplit<<<256, 64, 0, stream>>>(gW1, gW2, wf);

    // CSR: count + scan
    k_zero<<<(NN+255)/256, 256, 0, stream>>>(cur, NN);
    k_count<<<(NE+255)/256, 256, 0, stream>>>(eidx, cur);
    k_scan1<<<196, 256, 0, stream>>>(cur, iptr, bsum);
    k_scan2<<<1, 64, 0, stream>>>(bsum, iptr, 196);
    k_scan3<<<196, 256, 0, stream>>>(iptr, bsum, cur);
    // bucketed scatter (low write-amplification)
    k_bcur<<<(NBUK+255)/256, 256, 0, stream>>>(iptr, bcur);
    k_bucket<<<(NE+255)/256, 256, 0, stream>>>(eidx, bcur, tmp);
    k_place<<<NBUK, 256, 0, stream>>>(iptr, tmp, esrc);

    for (int l=0;l<4;l++){
        k_agg<<<NN/4, 256, 0, stream>>>(x, xb, iptr, esrc, h);
        k_gin_mfma<<<(NN+63)/64, 256, 0, stream>>>(h,
            gb1 + (size_t)l*H, gb2 + (size_t)l*H, wf, x, xb, l, (l<3)?1:0);
    }

    k_pool<<<NG, 128, 0, stream>>>(x, batch, aggr);
    k_head_dot<<<NG*4, 128, 0, stream>>>(aggr, hW1, hb1, hW2, ok);
    k_evid<<<(NG+255)/256, 256, 0, stream>>>(ok, hb2, out);
}

// Round 14
// 481.285 us; speedup vs baseline: 1.4989x; 1.4989x over previous
//
#include <hip/hip_runtime.h>
#include <stdint.h>

#define NN 50000
#define NE 800000
#define NG 512
#define H  128

typedef __attribute__((ext_vector_type(8))) short short8;
typedef __attribute__((ext_vector_type(16))) float f32x16;

union U4S8 { uint4 u; short8 s; };

__device__ __forceinline__ float softplusf(float x){
    return fmaxf(x, 0.f) + log1pf(expf(-fabsf(x)));
}

// round-to-nearest-even bf16 bits (high 16) of x
__device__ __forceinline__ unsigned rne_bf16_hi(float x){
    unsigned u = __float_as_uint(x);
    unsigned r = u + 0x7fffu + ((u >> 16) & 1u);
    return r & 0xffff0000u;
}

// split two fp32 into bf16-hi dword and bf16-lo dword (RNE split; residual ~2^-17)
__device__ __forceinline__ void split_pack(float x0, float x1, unsigned &hi, unsigned &lo){
    unsigned h0 = rne_bf16_hi(x0), h1 = rne_bf16_hi(x1);
    hi = (h0 >> 16) | h1;
    float l0 = x0 - __uint_as_float(h0);
    float l1 = x1 - __uint_as_float(h1);
    unsigned g0 = rne_bf16_hi(l0), g1 = rne_bf16_hi(l1);
    lo = (g0 >> 16) | g1;
}

// pack adjacent-lane pair into one bf16x2 dword; even lanes store
__device__ __forceinline__ void store_xb_pair(unsigned* __restrict__ xbu, int mm,
                                              int cp, int c31, int lane, float v0, float v1){
    float p0 = __shfl_xor(v0, 1);
    float p1 = __shfl_xor(v1, 1);
    if (!(lane & 1)){
        unsigned u0 = (rne_bf16_hi(v0) >> 16) | (rne_bf16_hi(p0) & 0xffff0000u);
        unsigned u1 = (rne_bf16_hi(v1) >> 16) | (rne_bf16_hi(p1) & 0xffff0000u);
        xbu[(size_t)mm*64 + 32*cp      + (c31>>1)] = u0;
        xbu[(size_t)mm*64 + 32*cp + 16 + (c31>>1)] = u1;
    }
}

// ---------------- sentinel writer ----------------
__global__ void k_sentinel(float* out, float val){
    int i = blockIdx.x*256 + threadIdx.x;
    if (i < 6*NG) out[i] = val;
}

// ---------------- GIN W pre-split into MFMA B-fragment order ----------------
__global__ __launch_bounds__(64) void k_wsplit(const float* __restrict__ gW1,
    const float* __restrict__ gW2, uint4* __restrict__ wf)
{
    int bid = blockIdx.x, lane = threadIdx.x;
    int mat = bid >> 5, ntg = (bid >> 3) & 3, ks = bid & 7;
    int l = mat >> 1;
    const float* W = (mat & 1) ? (gW2 + (size_t)l*H*H) : (gW1 + (size_t)l*H*H);
    int n  = ntg*32 + (lane & 31);
    int kb = ks*16 + (lane >> 5)*8;
    unsigned hi[4], lo[4];
#pragma unroll
    for (int d=0; d<4; d++){
        float x0 = W[(size_t)(kb + 2*d    )*H + n];
        float x1 = W[(size_t)(kb + 2*d + 1)*H + n];
        split_pack(x0, x1, hi[d], lo[d]);
    }
    int bh = ((mat*2 + 0)*4 + ntg)*8 + ks;
    int bl = ((mat*2 + 1)*4 + ntg)*8 + ks;
    wf[bh*64 + lane] = make_uint4(hi[0],hi[1],hi[2],hi[3]);
    wf[bl*64 + lane] = make_uint4(lo[0],lo[1],lo[2],lo[3]);
}

// ---------------- W_comb (256x128) pre-split ----------------
__global__ __launch_bounds__(64) void k_wsplit_embed(const float* __restrict__ Wc,
    uint4* __restrict__ wcf)
{
    int bid = blockIdx.x, lane = threadIdx.x;
    int ntg = bid >> 4, ks = bid & 15;
    int n  = ntg*32 + (lane & 31);
    int kb = ks*16 + (lane >> 5)*8;
    unsigned hi[4], lo[4];
#pragma unroll
    for (int d=0; d<4; d++){
        float x0 = Wc[(size_t)(kb + 2*d    )*H + n];
        float x1 = Wc[(size_t)(kb + 2*d + 1)*H + n];
        split_pack(x0, x1, hi[d], lo[d]);
    }
    wcf[((0*4 + ntg)*16 + ks)*64 + lane] = make_uint4(hi[0],hi[1],hi[2],hi[3]);
    wcf[((1*4 + ntg)*16 + ks)*64 + lane] = make_uint4(lo[0],lo[1],lo[2],lo[3]);
}

// ---------------- initial embedding via MFMA ----------------
__global__ __launch_bounds__(256) void k_embed_mfma(const int* __restrict__ z,
    const float* __restrict__ pos, const float* __restrict__ emb,
    const float* __restrict__ Wp, const float* __restrict__ bp,
    const float* __restrict__ bc, const uint4* __restrict__ wcf,
    float* __restrict__ xout, unsigned* __restrict__ xbu)
{
    __shared__ unsigned short AhiF[2*8*64*8];
    __shared__ unsigned short AloF[2*8*64*8];
    const int t = threadIdx.x, lane = t & 63, w = t >> 6;
    const int rt = w & 1, cp = w >> 1;
    const int mb = blockIdx.x * 64;
    const int c31 = lane & 31;
    const int q = lane >> 5;

    const int r = t >> 2, c4 = t & 3;
    const int gr = mb + r;
    const int gre = (gr < NN) ? gr : (NN-1);
    const int zr = z[gre];
    const float p0 = pos[gre*3+0], p1 = pos[gre*3+1], p2 = pos[gre*3+2];
    const int rt_s = r >> 5, r31s = r & 31;

    f32x16 acc0, acc1;
#pragma unroll
    for (int i=0;i<16;i++){ acc0[i]=0.f; acc1[i]=0.f; }

#pragma unroll
    for (int kh2=0; kh2<2; kh2++){
        if (kh2) __syncthreads();
#pragma unroll
        for (int i=0;i<8;i++){
            int cl = c4*4 + i*16;
            float4 v;
            if (kh2 == 0){
                v = *(const float4*)(emb + (size_t)zr*H + cl);
            } else {
                float4 w0 = *(const float4*)(Wp + cl);
                float4 w1 = *(const float4*)(Wp + H + cl);
                float4 w2 = *(const float4*)(Wp + 2*H + cl);
                float4 bb = *(const float4*)(bp + cl);
                v.x = p0*w0.x + p1*w1.x + p2*w2.x + bb.x;
                v.y = p0*w0.y + p1*w1.y + p2*w2.y + bb.y;
                v.z = p0*w0.z + p1*w1.z + p2*w2.z + bb.z;
                v.w = p0*w0.w + p1*w1.w + p2*w2.w + bb.w;
            }
            unsigned h0,l0,h1,l1;
            split_pack(v.x, v.y, h0, l0);
            split_pack(v.z, v.w, h1, l1);
            int idx = ((rt_s*8 + (cl>>4))*64 + ((cl>>3)&1)*32 + r31s)*8 + (cl & 7);
            *(uint2*)&AhiF[idx] = make_uint2(h0, h1);
            *(uint2*)&AloF[idx] = make_uint2(l0, l1);
        }
        __syncthreads();
#pragma unroll
        for (int ks=0; ks<8; ks++){
            int ksg = kh2*8 + ks;
            U4S8 ah, al, bh0, bl0, bh1, bl1;
            ah.u  = *(const uint4*)&AhiF[((rt*8+ks)*64 + lane)*8];
            al.u  = *(const uint4*)&AloF[((rt*8+ks)*64 + lane)*8];
            bh0.u = wcf[((0*4 + 2*cp+0)*16 + ksg)*64 + lane];
            bl0.u = wcf[((1*4 + 2*cp+0)*16 + ksg)*64 + lane];
            bh1.u = wcf[((0*4 + 2*cp+1)*16 + ksg)*64 + lane];
            bl1.u = wcf[((1*4 + 2*cp+1)*16 + ksg)*64 + lane];
            acc0 = __builtin_amdgcn_mfma_f32_32x32x16_bf16(ah.s, bh0.s, acc0, 0,0,0);
            acc0 = __builtin_amdgcn_mfma_f32_32x32x16_bf16(ah.s, bl0.s, acc0, 0,0,0);
            acc0 = __builtin_amdgcn_mfma_f32_32x32x16_bf16(al.s, bh0.s, acc0, 0,0,0);
            acc1 = __builtin_amdgcn_mfma_f32_32x32x16_bf16(ah.s, bh1.s, acc1, 0,0,0);
            acc1 = __builtin_amdgcn_mfma_f32_32x32x16_bf16(ah.s, bl1.s, acc1, 0,0,0);
            acc1 = __builtin_amdgcn_mfma_f32_32x32x16_bf16(al.s, bh1.s, acc1, 0,0,0);
        }
    }

    const float bva = bc[64*cp + c31], bvb = bc[64*cp + 32 + c31];
#pragma unroll
    for (int reg=0; reg<16; reg++){
        int row = 32*rt + (reg & 3) + 8*(reg >> 2) + 4*q;
        int mm = mb + row;
        if (mm < NN){
            float v0 = fmaxf(acc0[reg] + bva, 0.f);
            float v1 = fmaxf(acc1[reg] + bvb, 0.f);
            xout[(size_t)mm*H + 64*cp      + c31] = v0;
            xout[(size_t)mm*H + 64*cp + 32 + c31] = v1;
            store_xb_pair(xbu, mm, cp, c31, lane, v0, v1);
        }
    }
}

// ---------------- fused GIN MLP: LDS-staged bf16x2-split MFMA ----------------
__global__ __launch_bounds__(256) void k_gin_mfma(const float* __restrict__ hx,
    const float* __restrict__ b1, const float* __restrict__ b2,
    const uint4* __restrict__ wf, float* __restrict__ xout,
    unsigned* __restrict__ xbu, int l, int relu2)
{
    __shared__ unsigned short AhiF[2*8*64*8];
    __shared__ unsigned short AloF[2*8*64*8];
    const int t = threadIdx.x, lane = t & 63, w = t >> 6;
    const int rt = w & 1, cp = w >> 1;
    const int mb = blockIdx.x * 64;
    const int c31 = lane & 31;
    const int q = lane >> 5;

    {
        int r = t >> 2, c4 = t & 3;
        int gr = mb + r;
        const float* rowp = hx + (size_t)((gr < NN) ? gr : (NN-1))*H;
        int rt_s = r >> 5, r31 = r & 31;
#pragma unroll
        for (int i=0;i<8;i++){
            int col = c4*4 + i*16;
            float4 v = *(const float4*)(rowp + col);
            unsigned h0,l0,h1,l1;
            split_pack(v.x, v.y, h0, l0);
            split_pack(v.z, v.w, h1, l1);
            int idx = ((rt_s*8 + i)*64 + ((col>>3)&1)*32 + r31)*8 + (col & 7);
            *(uint2*)&AhiF[idx] = make_uint2(h0, h1);
            *(uint2*)&AloF[idx] = make_uint2(l0, l1);
        }
    }
    __syncthreads();

    const float bv1a = b1[64*cp + c31], bv1b = b1[64*cp + 32 + c31];
    const float bv2a = b2[64*cp + c31], bv2b = b2[64*cp + 32 + c31];
    const int mat1 = l*2, mat2 = l*2 + 1;

    f32x16 acc0, acc1;
#pragma unroll
    for (int i=0;i<16;i++){ acc0[i]=0.f; acc1[i]=0.f; }

#pragma unroll
    for (int ks=0; ks<8; ks++){
        U4S8 ah, al, bh0, bl0, bh1, bl1;
        ah.u  = *(const uint4*)&AhiF[((rt*8+ks)*64 + lane)*8];
        al.u  = *(const uint4*)&AloF[((rt*8+ks)*64 + lane)*8];
        bh0.u = wf[(((mat1*2+0)*4 + 2*cp+0)*8 + ks)*64 + lane];
        bl0.u = wf[(((mat1*2+1)*4 + 2*cp+0)*8 + ks)*64 + lane];
        bh1.u = wf[(((mat1*2+0)*4 + 2*cp+1)*8 + ks)*64 + lane];
        bl1.u = wf[(((mat1*2+1)*4 + 2*cp+1)*8 + ks)*64 + lane];
        acc0 = __builtin_amdgcn_mfma_f32_32x32x16_bf16(ah.s, bh0.s, acc0, 0,0,0);
        acc0 = __builtin_amdgcn_mfma_f32_32x32x16_bf16(ah.s, bl0.s, acc0, 0,0,0);
        acc0 = __builtin_amdgcn_mfma_f32_32x32x16_bf16(al.s, bh0.s, acc0, 0,0,0);
        acc1 = __builtin_amdgcn_mfma_f32_32x32x16_bf16(ah.s, bh1.s, acc1, 0,0,0);
        acc1 = __builtin_amdgcn_mfma_f32_32x32x16_bf16(ah.s, bl1.s, acc1, 0,0,0);
        acc1 = __builtin_amdgcn_mfma_f32_32x32x16_bf16(al.s, bh1.s, acc1, 0,0,0);
    }

    __syncthreads();
#pragma unroll
    for (int reg=0; reg<16; reg++){
        int r31o = (reg & 3) + 8*(reg >> 2) + 4*q;
        float v0 = fmaxf(acc0[reg] + bv1a, 0.f);
        float v1 = fmaxf(acc1[reg] + bv1b, 0.f);
        {
            int k = 64*cp + c31;
            int idx = ((rt*8 + (k>>4))*64 + ((k>>3)&1)*32 + r31o)*8 + (k & 7);
            unsigned hb = rne_bf16_hi(v0);
            AhiF[idx] = (unsigned short)(hb >> 16);
            AloF[idx] = (unsigned short)(rne_bf16_hi(v0 - __uint_as_float(hb)) >> 16);
        }
        {
            int k = 64*cp + 32 + c31;
            int idx = ((rt*8 + (k>>4))*64 + ((k>>3)&1)*32 + r31o)*8 + (k & 7);
            unsigned hb = rne_bf16_hi(v1);
            AhiF[idx] = (unsigned short)(hb >> 16);
            AloF[idx] = (unsigned short)(rne_bf16_hi(v1 - __uint_as_float(hb)) >> 16);
        }
    }
    __syncthreads();

#pragma unroll
    for (int i=0;i<16;i++){ acc0[i]=0.f; acc1[i]=0.f; }
#pragma unroll
    for (int ks=0; ks<8; ks++){
        U4S8 ah, al, bh0, bl0, bh1, bl1;
        ah.u  = *(const uint4*)&AhiF[((rt*8+ks)*64 + lane)*8];
        al.u  = *(const uint4*)&AloF[((rt*8+ks)*64 + lane)*8];
        bh0.u = wf[(((mat2*2+0)*4 + 2*cp+0)*8 + ks)*64 + lane];
        bl0.u = wf[(((mat2*2+1)*4 + 2*cp+0)*8 + ks)*64 + lane];
        bh1.u = wf[(((mat2*2+0)*4 + 2*cp+1)*8 + ks)*64 + lane];
        bl1.u = wf[(((mat2*2+1)*4 + 2*cp+1)*8 + ks)*64 + lane];
        acc0 = __builtin_amdgcn_mfma_f32_32x32x16_bf16(ah.s, bh0.s, acc0, 0,0,0);
        acc0 = __builtin_amdgcn_mfma_f32_32x32x16_bf16(ah.s, bl0.s, acc0, 0,0,0);
        acc0 = __builtin_amdgcn_mfma_f32_32x32x16_bf16(al.s, bh0.s, acc0, 0,0,0);
        acc1 = __builtin_amdgcn_mfma_f32_32x32x16_bf16(ah.s, bh1.s, acc1, 0,0,0);
        acc1 = __builtin_amdgcn_mfma_f32_32x32x16_bf16(ah.s, bl1.s, acc1, 0,0,0);
        acc1 = __builtin_amdgcn_mfma_f32_32x32x16_bf16(al.s, bh1.s, acc1, 0,0,0);
    }

#pragma unroll
    for (int reg=0; reg<16; reg++){
        int row = 32*rt + (reg & 3) + 8*(reg >> 2) + 4*q;
        int mm = mb + row;
        if (mm < NN){
            float v0 = acc0[reg] + bv2a;
            float v1 = acc1[reg] + bv2b;
            if (relu2){ v0 = fmaxf(v0, 0.f); v1 = fmaxf(v1, 0.f); }
            xout[(size_t)mm*H + 64*cp      + c31] = v0;
            xout[(size_t)mm*H + 64*cp + 32 + c31] = v1;
            store_xb_pair(xbu, mm, cp, c31, lane, v0, v1);
        }
    }
}

// ---------------- CSR build (by dst) — round-12 per-node-cursor version ----------------
__global__ void k_zero(int* p, int n){ int i=blockIdx.x*256+threadIdx.x; if(i<n) p[i]=0; }

__global__ void k_count(const int* __restrict__ ei, int* __restrict__ cnt){
    int e = blockIdx.x*256+threadIdx.x;
    if (e < NE){ int d = ei[NE+e]; if ((unsigned)d < NN) atomicAdd(&cnt[d], 1); }
}

__global__ __launch_bounds__(256) void k_scan1(const int* __restrict__ cnt,
    int* __restrict__ iptr, int* __restrict__ bsum)
{
    __shared__ int s[256];
    int t = threadIdx.x, i = blockIdx.x*256 + t;
    int v = (i < NN) ? cnt[i] : 0;
    s[t] = v;
    for (int off=1; off<256; off<<=1){
        __syncthreads();
        int tv = (t >= off) ? s[t-off] : 0;
        __syncthreads();
        s[t] += tv;
    }
    __syncthreads();
    if (i < NN) iptr[i] = s[t] - v;
    if (t == 255) bsum[blockIdx.x] = s[255];
}

__global__ void k_scan2(int* bsum, int* iptr, int nb){
    if (threadIdx.x==0 && blockIdx.x==0){
        int run = 0;
        for (int b=0;b<nb;b++){ int v=bsum[b]; bsum[b]=run; run+=v; }
        iptr[NN] = run;
    }
}

__global__ void k_scan3(int* __restrict__ iptr, const int* __restrict__ bsum,
                        int* __restrict__ cur)
{
    int i = blockIdx.x*256 + threadIdx.x;
    if (i < NN){ int v = iptr[i] + bsum[i>>8]; iptr[i]=v; cur[i]=v; }
}

__global__ void k_scatter(const int* __restrict__ ei, int* __restrict__ cur,
                          int* __restrict__ esrc)
{
    int e = blockIdx.x*256 + threadIdx.x;
    if (e < NE){
        int d = ei[NE+e];
        if ((unsigned)d < NN){
            int p = atomicAdd(&cur[d], 1);
            if ((unsigned)p < NE) esrc[p] = ei[e];
        }
    }
}

// ---------------- GIN aggregation: wave-per-node, bf16 gather, 8-deep ----------------
__global__ __launch_bounds__(256) void k_agg(const float* __restrict__ x,
    const unsigned* __restrict__ xbu,
    const int* __restrict__ iptr, const int* __restrict__ esrc, float* __restrict__ h)
{
    int node = blockIdx.x*4 + (threadIdx.x >> 6);
    int lane = threadIdx.x & 63;
    int s = __builtin_amdgcn_readfirstlane(iptr[node]);
    int e = __builtin_amdgcn_readfirstlane(iptr[node+1]);
    const float2* __restrict__ xp = (const float2*)x;
    float2 acc = xp[(size_t)node*64 + lane];
    float2 accb = make_float2(0.f, 0.f);
    int j = s;
#define BF2X(u) __uint_as_float((u) << 16)
#define BF2Y(u) __uint_as_float((u) & 0xffff0000u)
    for (; j+8 <= e; j += 8){
        int i0 = esrc[j+0], i1 = esrc[j+1], i2 = esrc[j+2], i3 = esrc[j+3];
        int i4 = esrc[j+4], i5 = esrc[j+5], i6 = esrc[j+6], i7 = esrc[j+7];
        unsigned u0 = xbu[(size_t)i0*64 + lane];
        unsigned u1 = xbu[(size_t)i1*64 + lane];
        unsigned u2 = xbu[(size_t)i2*64 + lane];
        unsigned u3 = xbu[(size_t)i3*64 + lane];
        unsigned u4 = xbu[(size_t)i4*64 + lane];
        unsigned u5 = xbu[(size_t)i5*64 + lane];
        unsigned u6 = xbu[(size_t)i6*64 + lane];
        unsigned u7 = xbu[(size_t)i7*64 + lane];
        acc.x  += (BF2X(u0) + BF2X(u1)) + (BF2X(u2) + BF2X(u3));
        acc.y  += (BF2Y(u0) + BF2Y(u1)) + (BF2Y(u2) + BF2Y(u3));
        accb.x += (BF2X(u4) + BF2X(u5)) + (BF2X(u6) + BF2X(u7));
        accb.y += (BF2Y(u4) + BF2Y(u5)) + (BF2Y(u6) + BF2Y(u7));
    }
    for (; j < e; j++){
        unsigned u = xbu[(size_t)esrc[j]*64 + lane];
        acc.x += BF2X(u); acc.y += BF2Y(u);
    }
#undef BF2X
#undef BF2Y
    acc.x += accb.x; acc.y += accb.y;
    ((float2*)h)[(size_t)node*64 + lane] = acc;
}

// ---------------- per-graph sum pooling ----------------
__global__ __launch_bounds__(128) void k_pool(const float* __restrict__ x,
    const int* __restrict__ batch, float* __restrict__ aggr)
{
    int g = blockIdx.x, c = threadIdx.x;
    int lo=0, hi=NN;
    while (lo<hi){ int mid=(lo+hi)>>1; if (batch[mid] < g) lo=mid+1; else hi=mid; }
    int s0 = lo;
    hi = NN;
    while (lo<hi){ int mid=(lo+hi)>>1; if (batch[mid] < g+1) lo=mid+1; else hi=mid; }
    int e0 = lo;
    float a0=0.f, a1=0.f, a2=0.f, a3=0.f;
    int i = s0;
    for (; i+4 <= e0; i += 4){
        a0 += x[(size_t)(i+0)*H + c];
        a1 += x[(size_t)(i+1)*H + c];
        a2 += x[(size_t)(i+2)*H + c];
        a3 += x[(size_t)(i+3)*H + c];
    }
    for (; i < e0; i++) a0 += x[(size_t)i*H + c];
    aggr[g*H + c] = (a0+a1) + (a2+a3);
}

// ---------------- heads: per-(graph,head) dot kernel ----------------
__global__ __launch_bounds__(128) void k_head_dot(const float* __restrict__ aggr,
    const float* __restrict__ W1, const float* __restrict__ b1,
    const float* __restrict__ W2, float* __restrict__ ok)
{
    __shared__ float a[H];
    __shared__ float red[H];
    int b = blockIdx.x, g = b >> 2, k = b & 3;
    int c = threadIdx.x;
    a[c] = aggr[g*H + c];
    __syncthreads();
    float acc = b1[k*H + c];
    const float* wp = W1 + (size_t)k*H*H + c;
#pragma unroll 8
    for (int q=0; q<H; q++) acc += a[q] * wp[(size_t)q*H];
    red[c] = fmaxf(acc, 0.f) * W2[k*H + c];
    __syncthreads();
    for (int sd=64; sd>0; sd>>=1){
        if (c < sd) red[c] += red[c+sd];
        __syncthreads();
    }
    if (c == 0) ok[b] = red[0];
}

// ---------------- evidential epilogue ----------------
__global__ void k_evid(const float* __restrict__ ok, const float* __restrict__ b2,
                       float* __restrict__ out)
{
    int g = blockIdx.x*256 + threadIdx.x;
    if (g >= NG) return;
    float o0 = ok[g*4+0] + b2[0];
    float o1 = ok[g*4+1] + b2[1];
    float o2 = ok[g*4+2] + b2[2];
    float o3 = ok[g*4+3] + b2[3];
    float alpha = fmaxf(softplusf(o0) + 1.f, 1.f + 1e-4f);
    float beta  = softplusf(o1);
    float nu    = softplusf(o2);
    float am1   = alpha - 1.f;
    float aleat = beta / am1;
    float epis  = beta / (am1 * nu);
    out[0*NG+g] = o3;
    out[1*NG+g] = aleat;
    out[2*NG+g] = epis;
    out[3*NG+g] = nu;
    out[4*NG+g] = alpha;
    out[5*NG+g] = beta;
}

extern "C" void kernel_launch(void* const* d_in, const int* in_sizes, int n_in,
                              void* d_out, int out_size, void* d_ws, size_t ws_size,
                              hipStream_t stream)
{
    const int*   z     = (const int*)d_in[0];
    const float* pos   = (const float*)d_in[1];
    const int*   batch = (const int*)d_in[2];
    const int*   eidx  = (const int*)d_in[3];
    const float* emb   = (const float*)d_in[4];
    const float* Wp    = (const float*)d_in[5];
    const float* bp    = (const float*)d_in[6];
    const float* Wc    = (const float*)d_in[7];
    const float* bc    = (const float*)d_in[8];
    const float* gW1   = (const float*)d_in[9];
    const float* gb1   = (const float*)d_in[10];
    const float* gW2   = (const float*)d_in[11];
    const float* gb2   = (const float*)d_in[12];
    const float* hW1   = (const float*)d_in[13];
    const float* hb1   = (const float*)d_in[14];
    const float* hW2   = (const float*)d_in[15];
    const float* hb2   = (const float*)d_in[16];
    float* out = (float*)d_out;

    bool ok_sizes = (n_in == 17)
        && in_sizes[0] == NN && in_sizes[1] == NN*3 && in_sizes[2] == NN
        && in_sizes[3] == 2*NE && in_sizes[4] == 100*H
        && in_sizes[7] == 2*H*H && in_sizes[9] == 4*H*H
        && in_sizes[13] == 4*H*H && in_sizes[16] == 4;
    if (!ok_sizes){ k_sentinel<<<12, 256, 0, stream>>>(out, 600000.0f); return; }

    const size_t OFF_X    = 256;
    const size_t OFF_H    = 25600256;
    const size_t OFF_XB   = 51200256;
    const size_t OFF_AGGR = 64000256;
    const size_t OFF_IPTR = 64262400;
    const size_t OFF_CUR  = 64462464;
    const size_t OFF_ESRC = 64662464;
    const size_t OFF_BSUM = 67862464;
    const size_t OFF_WF   = 67863296;
    const size_t OFF_WCF  = 68387584;
    const size_t OFF_OK   = 68518656;
    const size_t REQ      = 68526848;
    if (ws_size < REQ){ k_sentinel<<<12, 256, 0, stream>>>(out, 500000.0f); return; }

    char* ws = (char*)d_ws;
    float*    x    = (float*)(ws + OFF_X);
    float*    h    = (float*)(ws + OFF_H);
    unsigned* xb   = (unsigned*)(ws + OFF_XB);
    float*    aggr = (float*)(ws + OFF_AGGR);
    int*      iptr = (int*)(ws + OFF_IPTR);
    int*      cur  = (int*)(ws + OFF_CUR);
    int*      esrc = (int*)(ws + OFF_ESRC);
    int*      bsum = (int*)(ws + OFF_BSUM);
    uint4*    wf   = (uint4*)(ws + OFF_WF);
    uint4*    wcf  = (uint4*)(ws + OFF_WCF);
    float*    ok   = (float*)(ws + OFF_OK);

    k_wsplit_embed<<<64, 64, 0, stream>>>(Wc, wcf);
    k_embed_mfma<<<(NN+63)/64, 256, 0, stream>>>(z, pos, emb, Wp, bp, bc, wcf, x, xb);

    k_wsplit<<<256, 64, 0, stream>>>(gW1, gW2, wf);

    // CSR: count + scan + per-node-cursor scatter (round-12 proven path)
    k_zero<<<(NN+255)/256, 256, 0, stream>>>(cur, NN);
    k_count<<<(NE+255)/256, 256, 0, stream>>>(eidx, cur);
    k_scan1<<<196, 256, 0, stream>>>(cur, iptr, bsum);
    k_scan2<<<1, 64, 0, stream>>>(bsum, iptr, 196);
    k_scan3<<<196, 256, 0, stream>>>(iptr, bsum, cur);
    k_scatter<<<(NE+255)/256, 256, 0, stream>>>(eidx, cur, esrc);

    for (int l=0;l<4;l++){
        k_agg<<<NN/4, 256, 0, stream>>>(x, xb, iptr, esrc, h);
        k_gin_mfma<<<(NN+63)/64, 256, 0, stream>>>(h,
            gb1 + (size_t)l*H, gb2 + (size_t)l*H, wf, x, xb, l, (l<3)?1:0);
    }

    k_pool<<<NG, 128, 0, stream>>>(x, batch, aggr);
    k_head_dot<<<NG*4, 128, 0, stream>>>(aggr, hW1, hb1, hW2, ok);
    k_evid<<<(NG+255)/256, 256, 0, stream>>>(ok, hb2, out);
}

// Round 15
// 405.156 us; speedup vs baseline: 1.7806x; 1.1879x over previous
//
#include <hip/hip_runtime.h>
#include <stdint.h>

#define NN 50000
#define NE 800000
#define NG 512
#define H  128
#define NBK 196      // ceil(NN/256) node buckets
#define EPB 3125     // edges per partition block (NE/256)

typedef __attribute__((ext_vector_type(8))) short short8;
typedef __attribute__((ext_vector_type(16))) float f32x16;

union U4S8 { uint4 u; short8 s; };

__device__ __forceinline__ float softplusf(float x){
    return fmaxf(x, 0.f) + log1pf(expf(-fabsf(x)));
}

__device__ __forceinline__ unsigned rne_bf16_hi(float x){
    unsigned u = __float_as_uint(x);
    unsigned r = u + 0x7fffu + ((u >> 16) & 1u);
    return r & 0xffff0000u;
}

__device__ __forceinline__ void split_pack(float x0, float x1, unsigned &hi, unsigned &lo){
    unsigned h0 = rne_bf16_hi(x0), h1 = rne_bf16_hi(x1);
    hi = (h0 >> 16) | h1;
    float l0 = x0 - __uint_as_float(h0);
    float l1 = x1 - __uint_as_float(h1);
    unsigned g0 = rne_bf16_hi(l0), g1 = rne_bf16_hi(l1);
    lo = (g0 >> 16) | g1;
}

__device__ __forceinline__ void store_xb_pair(unsigned* __restrict__ xbu, int mm,
                                              int cp, int c31, int lane, float v0, float v1){
    float p0 = __shfl_xor(v0, 1);
    float p1 = __shfl_xor(v1, 1);
    if (!(lane & 1)){
        unsigned u0 = (rne_bf16_hi(v0) >> 16) | (rne_bf16_hi(p0) & 0xffff0000u);
        unsigned u1 = (rne_bf16_hi(v1) >> 16) | (rne_bf16_hi(p1) & 0xffff0000u);
        xbu[(size_t)mm*64 + 32*cp      + (c31>>1)] = u0;
        xbu[(size_t)mm*64 + 32*cp + 16 + (c31>>1)] = u1;
    }
}

// ---------------- sentinel writer ----------------
__global__ void k_sentinel(float* out, float val){
    int i = blockIdx.x*256 + threadIdx.x;
    if (i < 6*NG) out[i] = val;
}

// ---------------- GIN W pre-split into MFMA B-fragment order ----------------
__global__ __launch_bounds__(64) void k_wsplit(const float* __restrict__ gW1,
    const float* __restrict__ gW2, uint4* __restrict__ wf)
{
    int bid = blockIdx.x, lane = threadIdx.x;
    int mat = bid >> 5, ntg = (bid >> 3) & 3, ks = bid & 7;
    int l = mat >> 1;
    const float* W = (mat & 1) ? (gW2 + (size_t)l*H*H) : (gW1 + (size_t)l*H*H);
    int n  = ntg*32 + (lane & 31);
    int kb = ks*16 + (lane >> 5)*8;
    unsigned hi[4], lo[4];
#pragma unroll
    for (int d=0; d<4; d++){
        float x0 = W[(size_t)(kb + 2*d    )*H + n];
        float x1 = W[(size_t)(kb + 2*d + 1)*H + n];
        split_pack(x0, x1, hi[d], lo[d]);
    }
    int bh = ((mat*2 + 0)*4 + ntg)*8 + ks;
    int bl = ((mat*2 + 1)*4 + ntg)*8 + ks;
    wf[bh*64 + lane] = make_uint4(hi[0],hi[1],hi[2],hi[3]);
    wf[bl*64 + lane] = make_uint4(lo[0],lo[1],lo[2],lo[3]);
}

// ---------------- W_comb (256x128) pre-split ----------------
__global__ __launch_bounds__(64) void k_wsplit_embed(const float* __restrict__ Wc,
    uint4* __restrict__ wcf)
{
    int bid = blockIdx.x, lane = threadIdx.x;
    int ntg = bid >> 4, ks = bid & 15;
    int n  = ntg*32 + (lane & 31);
    int kb = ks*16 + (lane >> 5)*8;
    unsigned hi[4], lo[4];
#pragma unroll
    for (int d=0; d<4; d++){
        float x0 = Wc[(size_t)(kb + 2*d    )*H + n];
        float x1 = Wc[(size_t)(kb + 2*d + 1)*H + n];
        split_pack(x0, x1, hi[d], lo[d]);
    }
    wcf[((0*4 + ntg)*16 + ks)*64 + lane] = make_uint4(hi[0],hi[1],hi[2],hi[3]);
    wcf[((1*4 + ntg)*16 + ks)*64 + lane] = make_uint4(lo[0],lo[1],lo[2],lo[3]);
}

// ---------------- initial embedding via MFMA ----------------
__global__ __launch_bounds__(256) void k_embed_mfma(const int* __restrict__ z,
    const float* __restrict__ pos, const float* __restrict__ emb,
    const float* __restrict__ Wp, const float* __restrict__ bp,
    const float* __restrict__ bc, const uint4* __restrict__ wcf,
    float* __restrict__ xout, unsigned* __restrict__ xbu)
{
    __shared__ unsigned short AhiF[2*8*64*8];
    __shared__ unsigned short AloF[2*8*64*8];
    const int t = threadIdx.x, lane = t & 63, w = t >> 6;
    const int rt = w & 1, cp = w >> 1;
    const int mb = blockIdx.x * 64;
    const int c31 = lane & 31;
    const int q = lane >> 5;

    const int r = t >> 2, c4 = t & 3;
    const int gr = mb + r;
    const int gre = (gr < NN) ? gr : (NN-1);
    const int zr = z[gre];
    const float p0 = pos[gre*3+0], p1 = pos[gre*3+1], p2 = pos[gre*3+2];
    const int rt_s = r >> 5, r31s = r & 31;

    f32x16 acc0, acc1;
#pragma unroll
    for (int i=0;i<16;i++){ acc0[i]=0.f; acc1[i]=0.f; }

#pragma unroll
    for (int kh2=0; kh2<2; kh2++){
        if (kh2) __syncthreads();
#pragma unroll
        for (int i=0;i<8;i++){
            int cl = c4*4 + i*16;
            float4 v;
            if (kh2 == 0){
                v = *(const float4*)(emb + (size_t)zr*H + cl);
            } else {
                float4 w0 = *(const float4*)(Wp + cl);
                float4 w1 = *(const float4*)(Wp + H + cl);
                float4 w2 = *(const float4*)(Wp + 2*H + cl);
                float4 bb = *(const float4*)(bp + cl);
                v.x = p0*w0.x + p1*w1.x + p2*w2.x + bb.x;
                v.y = p0*w0.y + p1*w1.y + p2*w2.y + bb.y;
                v.z = p0*w0.z + p1*w1.z + p2*w2.z + bb.z;
                v.w = p0*w0.w + p1*w1.w + p2*w2.w + bb.w;
            }
            unsigned h0,l0,h1,l1;
            split_pack(v.x, v.y, h0, l0);
            split_pack(v.z, v.w, h1, l1);
            int idx = ((rt_s*8 + (cl>>4))*64 + ((cl>>3)&1)*32 + r31s)*8 + (cl & 7);
            *(uint2*)&AhiF[idx] = make_uint2(h0, h1);
            *(uint2*)&AloF[idx] = make_uint2(l0, l1);
        }
        __syncthreads();
#pragma unroll
        for (int ks=0; ks<8; ks++){
            int ksg = kh2*8 + ks;
            U4S8 ah, al, bh0, bl0, bh1, bl1;
            ah.u  = *(const uint4*)&AhiF[((rt*8+ks)*64 + lane)*8];
            al.u  = *(const uint4*)&AloF[((rt*8+ks)*64 + lane)*8];
            bh0.u = wcf[((0*4 + 2*cp+0)*16 + ksg)*64 + lane];
            bl0.u = wcf[((1*4 + 2*cp+0)*16 + ksg)*64 + lane];
            bh1.u = wcf[((0*4 + 2*cp+1)*16 + ksg)*64 + lane];
            bl1.u = wcf[((1*4 + 2*cp+1)*16 + ksg)*64 + lane];
            acc0 = __builtin_amdgcn_mfma_f32_32x32x16_bf16(ah.s, bh0.s, acc0, 0,0,0);
            acc0 = __builtin_amdgcn_mfma_f32_32x32x16_bf16(ah.s, bl0.s, acc0, 0,0,0);
            acc0 = __builtin_amdgcn_mfma_f32_32x32x16_bf16(al.s, bh0.s, acc0, 0,0,0);
            acc1 = __builtin_amdgcn_mfma_f32_32x32x16_bf16(ah.s, bh1.s, acc1, 0,0,0);
            acc1 = __builtin_amdgcn_mfma_f32_32x32x16_bf16(ah.s, bl1.s, acc1, 0,0,0);
            acc1 = __builtin_amdgcn_mfma_f32_32x32x16_bf16(al.s, bh1.s, acc1, 0,0,0);
        }
    }

    const float bva = bc[64*cp + c31], bvb = bc[64*cp + 32 + c31];
#pragma unroll
    for (int reg=0; reg<16; reg++){
        int row = 32*rt + (reg & 3) + 8*(reg >> 2) + 4*q;
        int mm = mb + row;
        if (mm < NN){
            float v0 = fmaxf(acc0[reg] + bva, 0.f);
            float v1 = fmaxf(acc1[reg] + bvb, 0.f);
            xout[(size_t)mm*H + 64*cp      + c31] = v0;
            xout[(size_t)mm*H + 64*cp + 32 + c31] = v1;
            store_xb_pair(xbu, mm, cp, c31, lane, v0, v1);
        }
    }
}

// ---------------- fused GIN MLP: LDS-staged bf16x2-split MFMA ----------------
__global__ __launch_bounds__(256) void k_gin_mfma(const float* __restrict__ hx,
    const float* __restrict__ b1, const float* __restrict__ b2,
    const uint4* __restrict__ wf, float* __restrict__ xout,
    unsigned* __restrict__ xbu, int l, int relu2)
{
    __shared__ unsigned short AhiF[2*8*64*8];
    __shared__ unsigned short AloF[2*8*64*8];
    const int t = threadIdx.x, lane = t & 63, w = t >> 6;
    const int rt = w & 1, cp = w >> 1;
    const int mb = blockIdx.x * 64;
    const int c31 = lane & 31;
    const int q = lane >> 5;

    {
        int r = t >> 2, c4 = t & 3;
        int gr = mb + r;
        const float* rowp = hx + (size_t)((gr < NN) ? gr : (NN-1))*H;
        int rt_s = r >> 5, r31 = r & 31;
#pragma unroll
        for (int i=0;i<8;i++){
            int col = c4*4 + i*16;
            float4 v = *(const float4*)(rowp + col);
            unsigned h0,l0,h1,l1;
            split_pack(v.x, v.y, h0, l0);
            split_pack(v.z, v.w, h1, l1);
            int idx = ((rt_s*8 + i)*64 + ((col>>3)&1)*32 + r31)*8 + (col & 7);
            *(uint2*)&AhiF[idx] = make_uint2(h0, h1);
            *(uint2*)&AloF[idx] = make_uint2(l0, l1);
        }
    }
    __syncthreads();

    const float bv1a = b1[64*cp + c31], bv1b = b1[64*cp + 32 + c31];
    const float bv2a = b2[64*cp + c31], bv2b = b2[64*cp + 32 + c31];
    const int mat1 = l*2, mat2 = l*2 + 1;

    f32x16 acc0, acc1;
#pragma unroll
    for (int i=0;i<16;i++){ acc0[i]=0.f; acc1[i]=0.f; }

#pragma unroll
    for (int ks=0; ks<8; ks++){
        U4S8 ah, al, bh0, bl0, bh1, bl1;
        ah.u  = *(const uint4*)&AhiF[((rt*8+ks)*64 + lane)*8];
        al.u  = *(const uint4*)&AloF[((rt*8+ks)*64 + lane)*8];
        bh0.u = wf[(((mat1*2+0)*4 + 2*cp+0)*8 + ks)*64 + lane];
        bl0.u = wf[(((mat1*2+1)*4 + 2*cp+0)*8 + ks)*64 + lane];
        bh1.u = wf[(((mat1*2+0)*4 + 2*cp+1)*8 + ks)*64 + lane];
        bl1.u = wf[(((mat1*2+1)*4 + 2*cp+1)*8 + ks)*64 + lane];
        acc0 = __builtin_amdgcn_mfma_f32_32x32x16_bf16(ah.s, bh0.s, acc0, 0,0,0);
        acc0 = __builtin_amdgcn_mfma_f32_32x32x16_bf16(ah.s, bl0.s, acc0, 0,0,0);
        acc0 = __builtin_amdgcn_mfma_f32_32x32x16_bf16(al.s, bh0.s, acc0, 0,0,0);
        acc1 = __builtin_amdgcn_mfma_f32_32x32x16_bf16(ah.s, bh1.s, acc1, 0,0,0);
        acc1 = __builtin_amdgcn_mfma_f32_32x32x16_bf16(ah.s, bl1.s, acc1, 0,0,0);
        acc1 = __builtin_amdgcn_mfma_f32_32x32x16_bf16(al.s, bh1.s, acc1, 0,0,0);
    }

    __syncthreads();
#pragma unroll
    for (int reg=0; reg<16; reg++){
        int r31o = (reg & 3) + 8*(reg >> 2) + 4*q;
        float v0 = fmaxf(acc0[reg] + bv1a, 0.f);
        float v1 = fmaxf(acc1[reg] + bv1b, 0.f);
        {
            int k = 64*cp + c31;
            int idx = ((rt*8 + (k>>4))*64 + ((k>>3)&1)*32 + r31o)*8 + (k & 7);
            unsigned hb = rne_bf16_hi(v0);
            AhiF[idx] = (unsigned short)(hb >> 16);
            AloF[idx] = (unsigned short)(rne_bf16_hi(v0 - __uint_as_float(hb)) >> 16);
        }
        {
            int k = 64*cp + 32 + c31;
            int idx = ((rt*8 + (k>>4))*64 + ((k>>3)&1)*32 + r31o)*8 + (k & 7);
            unsigned hb = rne_bf16_hi(v1);
            AhiF[idx] = (unsigned short)(hb >> 16);
            AloF[idx] = (unsigned short)(rne_bf16_hi(v1 - __uint_as_float(hb)) >> 16);
        }
    }
    __syncthreads();

#pragma unroll
    for (int i=0;i<16;i++){ acc0[i]=0.f; acc1[i]=0.f; }
#pragma unroll
    for (int ks=0; ks<8; ks++){
        U4S8 ah, al, bh0, bl0, bh1, bl1;
        ah.u  = *(const uint4*)&AhiF[((rt*8+ks)*64 + lane)*8];
        al.u  = *(const uint4*)&AloF[((rt*8+ks)*64 + lane)*8];
        bh0.u = wf[(((mat2*2+0)*4 + 2*cp+0)*8 + ks)*64 + lane];
        bl0.u = wf[(((mat2*2+1)*4 + 2*cp+0)*8 + ks)*64 + lane];
        bh1.u = wf[(((mat2*2+0)*4 + 2*cp+1)*8 + ks)*64 + lane];
        bl1.u = wf[(((mat2*2+1)*4 + 2*cp+1)*8 + ks)*64 + lane];
        acc0 = __builtin_amdgcn_mfma_f32_32x32x16_bf16(ah.s, bh0.s, acc0, 0,0,0);
        acc0 = __builtin_amdgcn_mfma_f32_32x32x16_bf16(ah.s, bl0.s, acc0, 0,0,0);
        acc0 = __builtin_amdgcn_mfma_f32_32x32x16_bf16(al.s, bh0.s, acc0, 0,0,0);
        acc1 = __builtin_amdgcn_mfma_f32_32x32x16_bf16(ah.s, bh1.s, acc1, 0,0,0);
        acc1 = __builtin_amdgcn_mfma_f32_32x32x16_bf16(ah.s, bl1.s, acc1, 0,0,0);
        acc1 = __builtin_amdgcn_mfma_f32_32x32x16_bf16(al.s, bh1.s, acc1, 0,0,0);
    }

#pragma unroll
    for (int reg=0; reg<16; reg++){
        int row = 32*rt + (reg & 3) + 8*(reg >> 2) + 4*q;
        int mm = mb + row;
        if (mm < NN){
            float v0 = acc0[reg] + bv2a;
            float v1 = acc1[reg] + bv2b;
            if (relu2){ v0 = fmaxf(v0, 0.f); v1 = fmaxf(v1, 0.f); }
            xout[(size_t)mm*H + 64*cp      + c31] = v0;
            xout[(size_t)mm*H + 64*cp + 32 + c31] = v1;
            store_xb_pair(xbu, mm, cp, c31, lane, v0, v1);
        }
    }
}

// ================ contention-free CSR build (two-level radix partition) ================
// Pass A: per-block LDS bucket histogram -> cnt[bucket*256 + block]
__global__ __launch_bounds__(256) void k_hist(const int* __restrict__ ei, int* __restrict__ cnt){
    __shared__ int hist[256];
    int blk = blockIdx.x, t = threadIdx.x;
    hist[t] = 0;
    __syncthreads();
    int e0 = blk*EPB, e1 = min(e0+EPB, NE);
    for (int e = e0+t; e < e1; e += 256){
        int d = ei[NE+e];
        if ((unsigned)d < NN) atomicAdd(&hist[d>>8], 1);
    }
    __syncthreads();
    if (t < NBK) cnt[t*256 + blk] = hist[t];
}

// Pass B1: bucket totals (coalesced column reduce)
__global__ __launch_bounds__(256) void k_btot(const int* __restrict__ cnt, int* __restrict__ tot){
    __shared__ int s[256];
    int k = blockIdx.x, t = threadIdx.x;
    s[t] = cnt[k*256 + t];
    __syncthreads();
    for (int sd=128; sd>0; sd>>=1){
        if (t < sd) s[t] += s[t+sd];
        __syncthreads();
    }
    if (t == 0) tot[k] = s[0];
}

// Pass B2: scan bucket totals -> bucket bases bb[0..NBK]
__global__ __launch_bounds__(256) void k_bscan(const int* __restrict__ tot, int* __restrict__ bb){
    __shared__ int sc[256];
    int t = threadIdx.x;
    int v = (t < NBK) ? tot[t] : 0;
    sc[t] = v;
    for (int off=1; off<256; off<<=1){
        __syncthreads();
        int tv = (t >= off) ? sc[t-off] : 0;
        __syncthreads();
        sc[t] += tv;
    }
    __syncthreads();
    if (t == 0) bb[0] = 0;
    if (t < NBK) bb[t+1] = sc[t];
}

// Pass B3: per-(bucket,block) start offsets soff[bucket*256+block]
__global__ __launch_bounds__(256) void k_soff(const int* __restrict__ cnt,
    const int* __restrict__ bb, int* __restrict__ soff)
{
    __shared__ int sc[256];
    int k = blockIdx.x, t = threadIdx.x;
    int v = cnt[k*256 + t];
    sc[t] = v;
    for (int off=1; off<256; off<<=1){
        __syncthreads();
        int tv = (t >= off) ? sc[t-off] : 0;
        __syncthreads();
        sc[t] += tv;
    }
    __syncthreads();
    soff[k*256 + t] = bb[k] + sc[t] - v;
}

// Pass C: LDS-reorder each block's edges by bucket, write contiguous runs to tmp2
__global__ __launch_bounds__(256) void k_part(const int* __restrict__ ei,
    const int* __restrict__ soff, uint2* __restrict__ tmp2)
{
    __shared__ int dstL[EPB];
    __shared__ int srcL[EPB];
    __shared__ int sc[256], startv[256], curv[256];
    __shared__ int tots;
    int blk = blockIdx.x, t = threadIdx.x;
    sc[t] = 0;
    __syncthreads();
    int e0 = blk*EPB, e1 = min(e0+EPB, NE);
    for (int e = e0+t; e < e1; e += 256){
        int d = ei[NE+e];
        if ((unsigned)d < NN) atomicAdd(&sc[d>>8], 1);
    }
    __syncthreads();
    int v = sc[t];
    for (int off=1; off<256; off<<=1){
        __syncthreads();
        int tv = (t >= off) ? sc[t-off] : 0;
        __syncthreads();
        sc[t] += tv;
    }
    __syncthreads();
    startv[t] = sc[t] - v;
    curv[t]   = sc[t] - v;
    if (t == 255) tots = sc[255];
    __syncthreads();
    for (int e = e0+t; e < e1; e += 256){
        int d = ei[NE+e];
        if ((unsigned)d < NN){
            int sv = ei[e];
            int p = atomicAdd(&curv[d>>8], 1);
            dstL[p] = d; srcL[p] = sv;
        }
    }
    __syncthreads();
    int nTot = tots;
    for (int i = t; i < nTot; i += 256){
        int d = dstL[i], b = d >> 8;
        int g = soff[b*256 + blk] + (i - startv[b]);
        tmp2[g] = make_uint2((unsigned)srcL[i], (unsigned)d);
    }
}

// Pass D: per-bucket node-level count+scan+place; emits esrc AND iptr
__global__ __launch_bounds__(256) void k_final(const int* __restrict__ bb,
    const uint2* __restrict__ tmp2, int* __restrict__ esrc, int* __restrict__ iptr)
{
    __shared__ int cntN[256], sc[256], curN[256];
    int k = blockIdx.x, t = threadIdx.x;
    int n0 = k*256;
    int nn = min(256, NN - n0);
    int base = bb[k], end = bb[k+1];
    cntN[t] = 0;
    __syncthreads();
    for (int i = base+t; i < end; i += 256){
        int d = (int)tmp2[i].y - n0;
        if ((unsigned)d < 256u) atomicAdd(&cntN[d], 1);
    }
    __syncthreads();
    int v = cntN[t];
    sc[t] = v;
    for (int off=1; off<256; off<<=1){
        __syncthreads();
        int tv = (t >= off) ? sc[t-off] : 0;
        __syncthreads();
        sc[t] += tv;
    }
    __syncthreads();
    int excl = sc[t] - v;
    curN[t] = excl;
    if (t < nn) iptr[n0 + t] = base + excl;
    if (k == NBK-1 && t == 0) iptr[NN] = end;
    __syncthreads();
    for (int i = base+t; i < end; i += 256){
        uint2 u = tmp2[i];
        int d = (int)u.y - n0;
        if ((unsigned)d < 256u){
            int p = atomicAdd(&curN[d], 1);
            esrc[base + p] = (int)u.x;
        }
    }
}

// ---------------- GIN aggregation: wave-per-node, bf16 gather, 16-deep ----------------
__global__ __launch_bounds__(256) void k_agg(const float* __restrict__ x,
    const unsigned* __restrict__ xbu,
    const int* __restrict__ iptr, const int* __restrict__ esrc, float* __restrict__ h)
{
    int node = blockIdx.x*4 + (threadIdx.x >> 6);
    int lane = threadIdx.x & 63;
    int s = __builtin_amdgcn_readfirstlane(iptr[node]);
    int e = __builtin_amdgcn_readfirstlane(iptr[node+1]);
    s = max(0, min(s, NE));
    e = max(s, min(e, NE));
    const float2* __restrict__ xp = (const float2*)x;
    float2 acc = xp[(size_t)node*64 + lane];
    float ax1=0.f, ay1=0.f, ax2=0.f, ay2=0.f, ax3=0.f, ay3=0.f;
    int j = s;
#define BF2X(u) __uint_as_float((u) << 16)
#define BF2Y(u) __uint_as_float((u) & 0xffff0000u)
    for (; j+16 <= e; j += 16){
        int idx[16];
#pragma unroll
        for (int u=0;u<16;u++) idx[u] = esrc[j+u];
        unsigned uv[16];
#pragma unroll
        for (int u=0;u<16;u++) uv[u] = xbu[(size_t)idx[u]*64 + lane];
        acc.x += (BF2X(uv[0]) + BF2X(uv[1])) + (BF2X(uv[2]) + BF2X(uv[3]));
        acc.y += (BF2Y(uv[0]) + BF2Y(uv[1])) + (BF2Y(uv[2]) + BF2Y(uv[3]));
        ax1   += (BF2X(uv[4]) + BF2X(uv[5])) + (BF2X(uv[6]) + BF2X(uv[7]));
        ay1   += (BF2Y(uv[4]) + BF2Y(uv[5])) + (BF2Y(uv[6]) + BF2Y(uv[7]));
        ax2   += (BF2X(uv[8]) + BF2X(uv[9])) + (BF2X(uv[10]) + BF2X(uv[11]));
        ay2   += (BF2Y(uv[8]) + BF2Y(uv[9])) + (BF2Y(uv[10]) + BF2Y(uv[11]));
        ax3   += (BF2X(uv[12]) + BF2X(uv[13])) + (BF2X(uv[14]) + BF2X(uv[15]));
        ay3   += (BF2Y(uv[12]) + BF2Y(uv[13])) + (BF2Y(uv[14]) + BF2Y(uv[15]));
    }
    for (; j+4 <= e; j += 4){
        int i0 = esrc[j+0], i1 = esrc[j+1], i2 = esrc[j+2], i3 = esrc[j+3];
        unsigned u0 = xbu[(size_t)i0*64 + lane];
        unsigned u1 = xbu[(size_t)i1*64 + lane];
        unsigned u2 = xbu[(size_t)i2*64 + lane];
        unsigned u3 = xbu[(size_t)i3*64 + lane];
        acc.x += (BF2X(u0) + BF2X(u1)) + (BF2X(u2) + BF2X(u3));
        acc.y += (BF2Y(u0) + BF2Y(u1)) + (BF2Y(u2) + BF2Y(u3));
    }
    for (; j < e; j++){
        unsigned u = xbu[(size_t)esrc[j]*64 + lane];
        acc.x += BF2X(u); acc.y += BF2Y(u);
    }
#undef BF2X
#undef BF2Y
    acc.x += (ax1 + ax2) + ax3;
    acc.y += (ay1 + ay2) + ay3;
    ((float2*)h)[(size_t)node*64 + lane] = acc;
}

// ---------------- per-graph sum pooling ----------------
__global__ __launch_bounds__(128) void k_pool(const float* __restrict__ x,
    const int* __restrict__ batch, float* __restrict__ aggr)
{
    int g = blockIdx.x, c = threadIdx.x;
    int lo=0, hi=NN;
    while (lo<hi){ int mid=(lo+hi)>>1; if (batch[mid] < g) lo=mid+1; else hi=mid; }
    int s0 = lo;
    hi = NN;
    while (lo<hi){ int mid=(lo+hi)>>1; if (batch[mid] < g+1) lo=mid+1; else hi=mid; }
    int e0 = lo;
    float a0=0.f, a1=0.f, a2=0.f, a3=0.f;
    int i = s0;
    for (; i+4 <= e0; i += 4){
        a0 += x[(size_t)(i+0)*H + c];
        a1 += x[(size_t)(i+1)*H + c];
        a2 += x[(size_t)(i+2)*H + c];
        a3 += x[(size_t)(i+3)*H + c];
    }
    for (; i < e0; i++) a0 += x[(size_t)i*H + c];
    aggr[g*H + c] = (a0+a1) + (a2+a3);
}

// ---------------- heads: per-(graph,head) dot kernel ----------------
__global__ __launch_bounds__(128) void k_head_dot(const float* __restrict__ aggr,
    const float* __restrict__ W1, const float* __restrict__ b1,
    const float* __restrict__ W2, float* __restrict__ ok)
{
    __shared__ float a[H];
    __shared__ float red[H];
    int b = blockIdx.x, g = b >> 2, k = b & 3;
    int c = threadIdx.x;
    a[c] = aggr[g*H + c];
    __syncthreads();
    float acc = b1[k*H + c];
    const float* wp = W1 + (size_t)k*H*H + c;
#pragma unroll 8
    for (int q=0; q<H; q++) acc += a[q] * wp[(size_t)q*H];
    red[c] = fmaxf(acc, 0.f) * W2[k*H + c];
    __syncthreads();
    for (int sd=64; sd>0; sd>>=1){
        if (c < sd) red[c] += red[c+sd];
        __syncthreads();
    }
    if (c == 0) ok[b] = red[0];
}

// ---------------- evidential epilogue ----------------
__global__ void k_evid(const float* __restrict__ ok, const float* __restrict__ b2,
                       float* __restrict__ out)
{
    int g = blockIdx.x*256 + threadIdx.x;
    if (g >= NG) return;
    float o0 = ok[g*4+0] + b2[0];
    float o1 = ok[g*4+1] + b2[1];
    float o2 = ok[g*4+2] + b2[2];
    float o3 = ok[g*4+3] + b2[3];
    float alpha = fmaxf(softplusf(o0) + 1.f, 1.f + 1e-4f);
    float beta  = softplusf(o1);
    float nu    = softplusf(o2);
    float am1   = alpha - 1.f;
    float aleat = beta / am1;
    float epis  = beta / (am1 * nu);
    out[0*NG+g] = o3;
    out[1*NG+g] = aleat;
    out[2*NG+g] = epis;
    out[3*NG+g] = nu;
    out[4*NG+g] = alpha;
    out[5*NG+g] = beta;
}

extern "C" void kernel_launch(void* const* d_in, const int* in_sizes, int n_in,
                              void* d_out, int out_size, void* d_ws, size_t ws_size,
                              hipStream_t stream)
{
    const int*   z     = (const int*)d_in[0];
    const float* pos   = (const float*)d_in[1];
    const int*   batch = (const int*)d_in[2];
    const int*   eidx  = (const int*)d_in[3];
    const float* emb   = (const float*)d_in[4];
    const float* Wp    = (const float*)d_in[5];
    const float* bp    = (const float*)d_in[6];
    const float* Wc    = (const float*)d_in[7];
    const float* bc    = (const float*)d_in[8];
    const float* gW1   = (const float*)d_in[9];
    const float* gb1   = (const float*)d_in[10];
    const float* gW2   = (const float*)d_in[11];
    const float* gb2   = (const float*)d_in[12];
    const float* hW1   = (const float*)d_in[13];
    const float* hb1   = (const float*)d_in[14];
    const float* hW2   = (const float*)d_in[15];
    const float* hb2   = (const float*)d_in[16];
    float* out = (float*)d_out;

    bool ok_sizes = (n_in == 17)
        && in_sizes[0] == NN && in_sizes[1] == NN*3 && in_sizes[2] == NN
        && in_sizes[3] == 2*NE && in_sizes[4] == 100*H
        && in_sizes[7] == 2*H*H && in_sizes[9] == 4*H*H
        && in_sizes[13] == 4*H*H && in_sizes[16] == 4;
    if (!ok_sizes){ k_sentinel<<<12, 256, 0, stream>>>(out, 600000.0f); return; }

    const size_t OFF_X    = 256;
    const size_t OFF_H    = 25600256;   // 25.6 MB; head reused pre-loop for CSR temps
    const size_t OFF_XB   = 51200256;
    const size_t OFF_AGGR = 64000256;
    const size_t OFF_IPTR = 64262400;
    const size_t OFF_ESRC = 64662464;
    const size_t OFF_WF   = 67863296;
    const size_t OFF_WCF  = 68387584;
    const size_t OFF_OK   = 68518656;
    const size_t REQ      = 68526848;
    if (ws_size < REQ){ k_sentinel<<<12, 256, 0, stream>>>(out, 500000.0f); return; }

    // CSR temps inside dead h region (used only before layer loop):
    const size_t OFF_TMP2 = OFF_H;              // NE * 8 B = 6.4 MB
    const size_t OFF_CNT  = OFF_H + 6400000;    // NBK*256*4 = 200,704
    const size_t OFF_SOFF = OFF_H + 6601216;    // 200,704
    const size_t OFF_TOT  = OFF_H + 6802176;    // 784
    const size_t OFF_BB   = OFF_H + 6803200;    // 788

    char* ws = (char*)d_ws;
    float*    x    = (float*)(ws + OFF_X);
    float*    h    = (float*)(ws + OFF_H);
    unsigned* xb   = (unsigned*)(ws + OFF_XB);
    float*    aggr = (float*)(ws + OFF_AGGR);
    int*      iptr = (int*)(ws + OFF_IPTR);
    int*      esrc = (int*)(ws + OFF_ESRC);
    uint4*    wf   = (uint4*)(ws + OFF_WF);
    uint4*    wcf  = (uint4*)(ws + OFF_WCF);
    float*    okb  = (float*)(ws + OFF_OK);
    uint2*    tmp2 = (uint2*)(ws + OFF_TMP2);
    int*      cnt  = (int*)(ws + OFF_CNT);
    int*      soff = (int*)(ws + OFF_SOFF);
    int*      tot  = (int*)(ws + OFF_TOT);
    int*      bb   = (int*)(ws + OFF_BB);

    k_wsplit_embed<<<64, 64, 0, stream>>>(Wc, wcf);
    k_embed_mfma<<<(NN+63)/64, 256, 0, stream>>>(z, pos, emb, Wp, bp, bc, wcf, x, xb);
    k_wsplit<<<256, 64, 0, stream>>>(gW1, gW2, wf);

    // contention-free CSR build
    k_hist <<<256, 256, 0, stream>>>(eidx, cnt);
    k_btot <<<NBK, 256, 0, stream>>>(cnt, tot);
    k_bscan<<<1,   256, 0, stream>>>(tot, bb);
    k_soff <<<NBK, 256, 0, stream>>>(cnt, bb, soff);
    k_part <<<256, 256, 0, stream>>>(eidx, soff, tmp2);
    k_final<<<NBK, 256, 0, stream>>>(bb, tmp2, esrc, iptr);

    for (int l=0;l<4;l++){
        k_agg<<<NN/4, 256, 0, stream>>>(x, xb, iptr, esrc, h);
        k_gin_mfma<<<(NN+63)/64, 256, 0, stream>>>(h,
            gb1 + (size_t)l*H, gb2 + (size_t)l*H, wf, x, xb, l, (l<3)?1:0);
    }

    k_pool<<<NG, 128, 0, stream>>>(x, batch, aggr);
    k_head_dot<<<NG*4, 128, 0, stream>>>(aggr, hW1, hb1, hW2, okb);
    k_evid<<<(NG+255)/256, 256, 0, stream>>>(okb, hb2, out);
}

// Round 16
// 396.350 us; speedup vs baseline: 1.8201x; 1.0222x over previous
//
#include <hip/hip_runtime.h>
#include <stdint.h>

#define NN 50000
#define NE 800000
#define NG 512
#define H  128
#define NBK 196      // ceil(NN/256) node buckets
#define EPB 3125     // edges per partition block (NE/256)

typedef __attribute__((ext_vector_type(8))) short short8;
typedef __attribute__((ext_vector_type(16))) float f32x16;

union U4S8 { uint4 u; short8 s; };

__device__ __forceinline__ float softplusf(float x){
    return fmaxf(x, 0.f) + log1pf(expf(-fabsf(x)));
}

__device__ __forceinline__ unsigned rne_bf16_hi(float x){
    unsigned u = __float_as_uint(x);
    unsigned r = u + 0x7fffu + ((u >> 16) & 1u);
    return r & 0xffff0000u;
}

__device__ __forceinline__ void split_pack(float x0, float x1, unsigned &hi, unsigned &lo){
    unsigned h0 = rne_bf16_hi(x0), h1 = rne_bf16_hi(x1);
    hi = (h0 >> 16) | h1;
    float l0 = x0 - __uint_as_float(h0);
    float l1 = x1 - __uint_as_float(h1);
    unsigned g0 = rne_bf16_hi(l0), g1 = rne_bf16_hi(l1);
    lo = (g0 >> 16) | g1;
}

// ---------------- sentinel writer ----------------
__global__ void k_sentinel(float* out, float val){
    int i = blockIdx.x*256 + threadIdx.x;
    if (i < 6*NG) out[i] = val;
}

// ---------------- GIN W pre-split into MFMA B-fragment order ----------------
// wf layout: [mat(8)][hl(2)][ntg(4)][ks(8)][lane(64)] x 16B.  mat = layer*2 + phase.
__global__ __launch_bounds__(64) void k_wsplit(const float* __restrict__ gW1,
    const float* __restrict__ gW2, uint4* __restrict__ wf)
{
    int bid = blockIdx.x, lane = threadIdx.x;
    int mat = bid >> 5, ntg = (bid >> 3) & 3, ks = bid & 7;
    int l = mat >> 1;
    const float* W = (mat & 1) ? (gW2 + (size_t)l*H*H) : (gW1 + (size_t)l*H*H);
    int n  = ntg*32 + (lane & 31);
    int kb = ks*16 + (lane >> 5)*8;
    unsigned hi[4], lo[4];
#pragma unroll
    for (int d=0; d<4; d++){
        float x0 = W[(size_t)(kb + 2*d    )*H + n];
        float x1 = W[(size_t)(kb + 2*d + 1)*H + n];
        split_pack(x0, x1, hi[d], lo[d]);
    }
    int bh = ((mat*2 + 0)*4 + ntg)*8 + ks;
    int bl = ((mat*2 + 1)*4 + ntg)*8 + ks;
    wf[bh*64 + lane] = make_uint4(hi[0],hi[1],hi[2],hi[3]);
    wf[bl*64 + lane] = make_uint4(lo[0],lo[1],lo[2],lo[3]);
}

// ---------------- W_comb (256x128) pre-split ----------------
__global__ __launch_bounds__(64) void k_wsplit_embed(const float* __restrict__ Wc,
    uint4* __restrict__ wcf)
{
    int bid = blockIdx.x, lane = threadIdx.x;
    int ntg = bid >> 4, ks = bid & 15;
    int n  = ntg*32 + (lane & 31);
    int kb = ks*16 + (lane >> 5)*8;
    unsigned hi[4], lo[4];
#pragma unroll
    for (int d=0; d<4; d++){
        float x0 = Wc[(size_t)(kb + 2*d    )*H + n];
        float x1 = Wc[(size_t)(kb + 2*d + 1)*H + n];
        split_pack(x0, x1, hi[d], lo[d]);
    }
    wcf[((0*4 + ntg)*16 + ks)*64 + lane] = make_uint4(hi[0],hi[1],hi[2],hi[3]);
    wcf[((1*4 + ntg)*16 + ks)*64 + lane] = make_uint4(lo[0],lo[1],lo[2],lo[3]);
}

// ---------------- initial embedding via MFMA (writes xA + xbA) ----------------
__global__ __launch_bounds__(256) void k_embed_mfma(const int* __restrict__ z,
    const float* __restrict__ pos, const float* __restrict__ emb,
    const float* __restrict__ Wp, const float* __restrict__ bp,
    const float* __restrict__ bc, const uint4* __restrict__ wcf,
    float* __restrict__ xout, unsigned* __restrict__ xbu)
{
    __shared__ unsigned short AhiF[2*8*64*8];
    __shared__ unsigned short AloF[2*8*64*8];
    const int t = threadIdx.x, lane = t & 63, w = t >> 6;
    const int rt = w & 1, cp = w >> 1;
    const int mb = blockIdx.x * 64;
    const int c31 = lane & 31;
    const int q = lane >> 5;

    const int r = t >> 2, c4 = t & 3;
    const int gr = mb + r;
    const int gre = (gr < NN) ? gr : (NN-1);
    const int zr = z[gre];
    const float p0 = pos[gre*3+0], p1 = pos[gre*3+1], p2 = pos[gre*3+2];
    const int rt_s = r >> 5, r31s = r & 31;

    f32x16 acc0, acc1;
#pragma unroll
    for (int i=0;i<16;i++){ acc0[i]=0.f; acc1[i]=0.f; }

#pragma unroll
    for (int kh2=0; kh2<2; kh2++){
        if (kh2) __syncthreads();
#pragma unroll
        for (int i=0;i<8;i++){
            int cl = c4*4 + i*16;
            float4 v;
            if (kh2 == 0){
                v = *(const float4*)(emb + (size_t)zr*H + cl);
            } else {
                float4 w0 = *(const float4*)(Wp + cl);
                float4 w1 = *(const float4*)(Wp + H + cl);
                float4 w2 = *(const float4*)(Wp + 2*H + cl);
                float4 bb = *(const float4*)(bp + cl);
                v.x = p0*w0.x + p1*w1.x + p2*w2.x + bb.x;
                v.y = p0*w0.y + p1*w1.y + p2*w2.y + bb.y;
                v.z = p0*w0.z + p1*w1.z + p2*w2.z + bb.z;
                v.w = p0*w0.w + p1*w1.w + p2*w2.w + bb.w;
            }
            unsigned h0,l0,h1,l1;
            split_pack(v.x, v.y, h0, l0);
            split_pack(v.z, v.w, h1, l1);
            int idx = ((rt_s*8 + (cl>>4))*64 + ((cl>>3)&1)*32 + r31s)*8 + (cl & 7);
            *(uint2*)&AhiF[idx] = make_uint2(h0, h1);
            *(uint2*)&AloF[idx] = make_uint2(l0, l1);
        }
        __syncthreads();
#pragma unroll
        for (int ks=0; ks<8; ks++){
            int ksg = kh2*8 + ks;
            U4S8 ah, al, bh0, bl0, bh1, bl1;
            ah.u  = *(const uint4*)&AhiF[((rt*8+ks)*64 + lane)*8];
            al.u  = *(const uint4*)&AloF[((rt*8+ks)*64 + lane)*8];
            bh0.u = wcf[((0*4 + 2*cp+0)*16 + ksg)*64 + lane];
            bl0.u = wcf[((1*4 + 2*cp+0)*16 + ksg)*64 + lane];
            bh1.u = wcf[((0*4 + 2*cp+1)*16 + ksg)*64 + lane];
            bl1.u = wcf[((1*4 + 2*cp+1)*16 + ksg)*64 + lane];
            acc0 = __builtin_amdgcn_mfma_f32_32x32x16_bf16(ah.s, bh0.s, acc0, 0,0,0);
            acc0 = __builtin_amdgcn_mfma_f32_32x32x16_bf16(ah.s, bl0.s, acc0, 0,0,0);
            acc0 = __builtin_amdgcn_mfma_f32_32x32x16_bf16(al.s, bh0.s, acc0, 0,0,0);
            acc1 = __builtin_amdgcn_mfma_f32_32x32x16_bf16(ah.s, bh1.s, acc1, 0,0,0);
            acc1 = __builtin_amdgcn_mfma_f32_32x32x16_bf16(ah.s, bl1.s, acc1, 0,0,0);
            acc1 = __builtin_amdgcn_mfma_f32_32x32x16_bf16(al.s, bh1.s, acc1, 0,0,0);
        }
    }

    const float bva = bc[64*cp + c31], bvb = bc[64*cp + 32 + c31];
#pragma unroll
    for (int reg=0; reg<16; reg++){
        int row = 32*rt + (reg & 3) + 8*(reg >> 2) + 4*q;
        int mm = mb + row;
        if (mm < NN){
            float v0 = fmaxf(acc0[reg] + bva, 0.f);
            float v1 = fmaxf(acc1[reg] + bvb, 0.f);
            xout[(size_t)mm*H + 64*cp      + c31] = v0;
            xout[(size_t)mm*H + 64*cp + 32 + c31] = v1;
            float pa = __shfl_xor(v0, 1);
            float pb = __shfl_xor(v1, 1);
            if (!(lane & 1)){
                unsigned u0 = (rne_bf16_hi(v0) >> 16) | (rne_bf16_hi(pa) & 0xffff0000u);
                unsigned u1 = (rne_bf16_hi(v1) >> 16) | (rne_bf16_hi(pb) & 0xffff0000u);
                xbu[(size_t)mm*64 + 32*cp      + (c31>>1)] = u0;
                xbu[(size_t)mm*64 + 32*cp + 16 + (c31>>1)] = u1;
            }
        }
    }
}

// ---------------- FUSED GIN layer: aggregation + 2-phase MFMA MLP ----------------
// Tile 32 rows x 128 cols; 256 thr = 4 waves; wave w = col tile w (n in [w*32,w*32+32)).
// Aggregation: wave w gathers rows w*8..w*8+7 (16-deep bf16 gather, identical to old k_agg),
// result split to bf16 hi/lo DIRECTLY into frag-order LDS (h never touches global).
// Double-buffered I/O: reads (xin, xbin), writes (xout, xbout).
__global__ __launch_bounds__(256) void k_gin_fused(
    const float* __restrict__ xin, const unsigned* __restrict__ xbin,
    const int* __restrict__ iptr, const int* __restrict__ esrc,
    const float* __restrict__ b1, const float* __restrict__ b2,
    const uint4* __restrict__ wf,
    float* __restrict__ xout, unsigned* __restrict__ xbout,
    int l, int relu2)
{
    __shared__ unsigned short AhiF[8*64*8];   // 8 KB
    __shared__ unsigned short AloF[8*64*8];   // 8 KB
    const int t = threadIdx.x, lane = t & 63, w = t >> 6;
    const int mb = blockIdx.x * 32;
    const int c31 = lane & 31;
    const int q = lane >> 5;

    // ---- fused aggregation: wave w handles rows w*8 .. w*8+7 ----
    const float2* __restrict__ xp = (const float2*)xin;
#define BF2X(u) __uint_as_float((u) << 16)
#define BF2Y(u) __uint_as_float((u) & 0xffff0000u)
    for (int rr = w*8; rr < w*8+8; rr++){
        int mm = mb + rr;
        int mme = (mm < NN) ? mm : (NN-1);
        int s = __builtin_amdgcn_readfirstlane(iptr[mme]);
        int e = __builtin_amdgcn_readfirstlane(iptr[mme+1]);
        s = max(0, min(s, NE));
        e = max(s, min(e, NE));
        float2 acc = xp[(size_t)mme*64 + lane];
        float ax1=0.f, ay1=0.f, ax2=0.f, ay2=0.f, ax3=0.f, ay3=0.f;
        int j = s;
        for (; j+16 <= e; j += 16){
            int idx[16];
#pragma unroll
            for (int u=0;u<16;u++) idx[u] = esrc[j+u];
            unsigned uv[16];
#pragma unroll
            for (int u=0;u<16;u++) uv[u] = xbin[(size_t)idx[u]*64 + lane];
            acc.x += (BF2X(uv[0]) + BF2X(uv[1])) + (BF2X(uv[2]) + BF2X(uv[3]));
            acc.y += (BF2Y(uv[0]) + BF2Y(uv[1])) + (BF2Y(uv[2]) + BF2Y(uv[3]));
            ax1   += (BF2X(uv[4]) + BF2X(uv[5])) + (BF2X(uv[6]) + BF2X(uv[7]));
            ay1   += (BF2Y(uv[4]) + BF2Y(uv[5])) + (BF2Y(uv[6]) + BF2Y(uv[7]));
            ax2   += (BF2X(uv[8]) + BF2X(uv[9])) + (BF2X(uv[10]) + BF2X(uv[11]));
            ay2   += (BF2Y(uv[8]) + BF2Y(uv[9])) + (BF2Y(uv[10]) + BF2Y(uv[11]));
            ax3   += (BF2X(uv[12]) + BF2X(uv[13])) + (BF2X(uv[14]) + BF2X(uv[15]));
            ay3   += (BF2Y(uv[12]) + BF2Y(uv[13])) + (BF2Y(uv[14]) + BF2Y(uv[15]));
        }
        for (; j+4 <= e; j += 4){
            int i0 = esrc[j+0], i1 = esrc[j+1], i2 = esrc[j+2], i3 = esrc[j+3];
            unsigned u0 = xbin[(size_t)i0*64 + lane];
            unsigned u1 = xbin[(size_t)i1*64 + lane];
            unsigned u2 = xbin[(size_t)i2*64 + lane];
            unsigned u3 = xbin[(size_t)i3*64 + lane];
            acc.x += (BF2X(u0) + BF2X(u1)) + (BF2X(u2) + BF2X(u3));
            acc.y += (BF2Y(u0) + BF2Y(u1)) + (BF2Y(u2) + BF2Y(u3));
        }
        for (; j < e; j++){
            unsigned u = xbin[(size_t)esrc[j]*64 + lane];
            acc.x += BF2X(u); acc.y += BF2Y(u);
        }
        acc.x += (ax1 + ax2) + ax3;
        acc.y += (ay1 + ay2) + ay3;
        // split h-row into bf16 hi/lo frag-order LDS; cols k0=2*lane, k1=2*lane+1
        {
            int k0 = 2*lane, k1 = k0 + 1;
            unsigned h0 = rne_bf16_hi(acc.x);
            unsigned g0 = rne_bf16_hi(acc.x - __uint_as_float(h0));
            unsigned h1 = rne_bf16_hi(acc.y);
            unsigned g1 = rne_bf16_hi(acc.y - __uint_as_float(h1));
            int i0 = ((k0>>4)*64 + ((k0>>3)&1)*32 + rr)*8 + (k0&7);
            int i1 = ((k1>>4)*64 + ((k1>>3)&1)*32 + rr)*8 + (k1&7);
            AhiF[i0] = (unsigned short)(h0 >> 16);
            AloF[i0] = (unsigned short)(g0 >> 16);
            AhiF[i1] = (unsigned short)(h1 >> 16);
            AloF[i1] = (unsigned short)(g1 >> 16);
        }
    }
#undef BF2X
#undef BF2Y
    __syncthreads();

    const float bv1 = b1[w*32 + c31];
    const float bv2 = b2[w*32 + c31];
    const int mat1 = l*2, mat2 = l*2 + 1;

    f32x16 acc;
#pragma unroll
    for (int i=0;i<16;i++) acc[i] = 0.f;

    // ---- phase 1: T = relu(h@W1 + b1), cols [w*32, w*32+32) ----
#pragma unroll
    for (int ks=0; ks<8; ks++){
        U4S8 ah, al, bh, bl;
        ah.u = *(const uint4*)&AhiF[(ks*64 + lane)*8];
        al.u = *(const uint4*)&AloF[(ks*64 + lane)*8];
        bh.u = wf[(((mat1*2+0)*4 + w)*8 + ks)*64 + lane];
        bl.u = wf[(((mat1*2+1)*4 + w)*8 + ks)*64 + lane];
        acc = __builtin_amdgcn_mfma_f32_32x32x16_bf16(ah.s, bh.s, acc, 0,0,0);
        acc = __builtin_amdgcn_mfma_f32_32x32x16_bf16(ah.s, bl.s, acc, 0,0,0);
        acc = __builtin_amdgcn_mfma_f32_32x32x16_bf16(al.s, bh.s, acc, 0,0,0);
    }

    // ---- T -> LDS frag-order (bf16 hi/lo) ----
    __syncthreads();
#pragma unroll
    for (int reg=0; reg<16; reg++){
        int r31o = (reg & 3) + 8*(reg >> 2) + 4*q;
        float v = fmaxf(acc[reg] + bv1, 0.f);
        int k = w*32 + c31;
        int idx = ((k>>4)*64 + ((k>>3)&1)*32 + r31o)*8 + (k & 7);
        unsigned hb = rne_bf16_hi(v);
        AhiF[idx] = (unsigned short)(hb >> 16);
        AloF[idx] = (unsigned short)(rne_bf16_hi(v - __uint_as_float(hb)) >> 16);
    }
    __syncthreads();

    // ---- phase 2: Y = T@W2 + b2 ----
#pragma unroll
    for (int i=0;i<16;i++) acc[i] = 0.f;
#pragma unroll
    for (int ks=0; ks<8; ks++){
        U4S8 ah, al, bh, bl;
        ah.u = *(const uint4*)&AhiF[(ks*64 + lane)*8];
        al.u = *(const uint4*)&AloF[(ks*64 + lane)*8];
        bh.u = wf[(((mat2*2+0)*4 + w)*8 + ks)*64 + lane];
        bl.u = wf[(((mat2*2+1)*4 + w)*8 + ks)*64 + lane];
        acc = __builtin_amdgcn_mfma_f32_32x32x16_bf16(ah.s, bh.s, acc, 0,0,0);
        acc = __builtin_amdgcn_mfma_f32_32x32x16_bf16(ah.s, bl.s, acc, 0,0,0);
        acc = __builtin_amdgcn_mfma_f32_32x32x16_bf16(al.s, bh.s, acc, 0,0,0);
    }

    // ---- epilogue: fp32 + bf16 copy to global (double-buffered out) ----
#pragma unroll
    for (int reg=0; reg<16; reg++){
        int row = (reg & 3) + 8*(reg >> 2) + 4*q;
        int mm = mb + row;
        if (mm < NN){
            float v = acc[reg] + bv2;
            if (relu2) v = fmaxf(v, 0.f);
            xout[(size_t)mm*H + w*32 + c31] = v;
            float p = __shfl_xor(v, 1);
            if (!(lane & 1)){
                unsigned u = (rne_bf16_hi(v) >> 16) | (rne_bf16_hi(p) & 0xffff0000u);
                xbout[(size_t)mm*64 + w*16 + (c31>>1)] = u;
            }
        }
    }
}

// ================ contention-free CSR build (two-level radix partition) ================
// Pass A: per-block LDS bucket histogram -> cnt[bucket*256 + block]
__global__ __launch_bounds__(256) void k_hist(const int* __restrict__ ei, int* __restrict__ cnt){
    __shared__ int hist[256];
    int blk = blockIdx.x, t = threadIdx.x;
    hist[t] = 0;
    __syncthreads();
    int e0 = blk*EPB, e1 = min(e0+EPB, NE);
    for (int e = e0+t; e < e1; e += 256){
        int d = ei[NE+e];
        if ((unsigned)d < NN) atomicAdd(&hist[d>>8], 1);
    }
    __syncthreads();
    if (t < NBK) cnt[t*256 + blk] = hist[t];
}

// Pass B1: bucket totals
__global__ __launch_bounds__(256) void k_btot(const int* __restrict__ cnt, int* __restrict__ tot){
    __shared__ int s[256];
    int k = blockIdx.x, t = threadIdx.x;
    s[t] = cnt[k*256 + t];
    __syncthreads();
    for (int sd=128; sd>0; sd>>=1){
        if (t < sd) s[t] += s[t+sd];
        __syncthreads();
    }
    if (t == 0) tot[k] = s[0];
}

// Pass B2: scan bucket totals -> bucket bases bb[0..NBK]
__global__ __launch_bounds__(256) void k_bscan(const int* __restrict__ tot, int* __restrict__ bb){
    __shared__ int sc[256];
    int t = threadIdx.x;
    int v = (t < NBK) ? tot[t] : 0;
    sc[t] = v;
    for (int off=1; off<256; off<<=1){
        __syncthreads();
        int tv = (t >= off) ? sc[t-off] : 0;
        __syncthreads();
        sc[t] += tv;
    }
    __syncthreads();
    if (t == 0) bb[0] = 0;
    if (t < NBK) bb[t+1] = sc[t];
}

// Pass B3: per-(bucket,block) start offsets
__global__ __launch_bounds__(256) void k_soff(const int* __restrict__ cnt,
    const int* __restrict__ bb, int* __restrict__ soff)
{
    __shared__ int sc[256];
    int k = blockIdx.x, t = threadIdx.x;
    int v = cnt[k*256 + t];
    sc[t] = v;
    for (int off=1; off<256; off<<=1){
        __syncthreads();
        int tv = (t >= off) ? sc[t-off] : 0;
        __syncthreads();
        sc[t] += tv;
    }
    __syncthreads();
    soff[k*256 + t] = bb[k] + sc[t] - v;
}

// Pass C: LDS-reorder each block's edges by bucket; packed (src | dst<<16) dword
__global__ __launch_bounds__(256) void k_part(const int* __restrict__ ei,
    const int* __restrict__ soff, unsigned* __restrict__ tmp)
{
    __shared__ unsigned edgeL[EPB];
    __shared__ int sc[256], startv[256], curv[256];
    __shared__ int tots;
    int blk = blockIdx.x, t = threadIdx.x;
    sc[t] = 0;
    __syncthreads();
    int e0 = blk*EPB, e1 = min(e0+EPB, NE);
    for (int e = e0+t; e < e1; e += 256){
        int d = ei[NE+e];
        if ((unsigned)d < NN) atomicAdd(&sc[d>>8], 1);
    }
    __syncthreads();
    int v = sc[t];
    for (int off=1; off<256; off<<=1){
        __syncthreads();
        int tv = (t >= off) ? sc[t-off] : 0;
        __syncthreads();
        sc[t] += tv;
    }
    __syncthreads();
    startv[t] = sc[t] - v;
    curv[t]   = sc[t] - v;
    if (t == 255) tots = sc[255];
    __syncthreads();
    for (int e = e0+t; e < e1; e += 256){
        int d = ei[NE+e];
        if ((unsigned)d < NN){
            unsigned u = (unsigned)ei[e] | ((unsigned)d << 16);
            int p = atomicAdd(&curv[d>>8], 1);
            edgeL[p] = u;
        }
    }
    __syncthreads();
    int nTot = tots;
    for (int i = t; i < nTot; i += 256){
        unsigned u = edgeL[i];
        int b = u >> 24;   // (dst>>8): bucket (dst<65536 so >>24 == (dst>>16)>>8... dst<<16>>24 = dst>>8) ✓
        int g = soff[b*256 + blk] + (i - startv[b]);
        tmp[g] = u;
    }
}

// Pass D: per-bucket node-level count+scan+place; emits esrc AND iptr
__global__ __launch_bounds__(256) void k_final(const int* __restrict__ bb,
    const unsigned* __restrict__ tmp, int* __restrict__ esrc, int* __restrict__ iptr)
{
    __shared__ int cntN[256], sc[256], curN[256];
    int k = blockIdx.x, t = threadIdx.x;
    int n0 = k*256;
    int nn = min(256, NN - n0);
    int base = bb[k], end = bb[k+1];
    cntN[t] = 0;
    __syncthreads();
    for (int i = base+t; i < end; i += 256){
        int d = (int)(tmp[i] >> 16) - n0;
        if ((unsigned)d < 256u) atomicAdd(&cntN[d], 1);
    }
    __syncthreads();
    int v = cntN[t];
    sc[t] = v;
    for (int off=1; off<256; off<<=1){
        __syncthreads();
        int tv = (t >= off) ? sc[t-off] : 0;
        __syncthreads();
        sc[t] += tv;
    }
    __syncthreads();
    int excl = sc[t] - v;
    curN[t] = excl;
    if (t < nn) iptr[n0 + t] = base + excl;
    if (k == NBK-1 && t == 0) iptr[NN] = end;
    __syncthreads();
    for (int i = base+t; i < end; i += 256){
        unsigned u = tmp[i];
        int d = (int)(u >> 16) - n0;
        if ((unsigned)d < 256u){
            int p = atomicAdd(&curN[d], 1);
            esrc[base + p] = (int)(u & 0xffffu);
        }
    }
}

// ---------------- per-graph sum pooling ----------------
__global__ __launch_bounds__(128) void k_pool(const float* __restrict__ x,
    const int* __restrict__ batch, float* __restrict__ aggr)
{
    int g = blockIdx.x, c = threadIdx.x;
    int lo=0, hi=NN;
    while (lo<hi){ int mid=(lo+hi)>>1; if (batch[mid] < g) lo=mid+1; else hi=mid; }
    int s0 = lo;
    hi = NN;
    while (lo<hi){ int mid=(lo+hi)>>1; if (batch[mid] < g+1) lo=mid+1; else hi=mid; }
    int e0 = lo;
    float a0=0.f, a1=0.f, a2=0.f, a3=0.f;
    int i = s0;
    for (; i+4 <= e0; i += 4){
        a0 += x[(size_t)(i+0)*H + c];
        a1 += x[(size_t)(i+1)*H + c];
        a2 += x[(size_t)(i+2)*H + c];
        a3 += x[(size_t)(i+3)*H + c];
    }
    for (; i < e0; i++) a0 += x[(size_t)i*H + c];
    aggr[g*H + c] = (a0+a1) + (a2+a3);
}

// ---------------- heads: per-(graph,head) dot kernel ----------------
__global__ __launch_bounds__(128) void k_head_dot(const float* __restrict__ aggr,
    const float* __restrict__ W1, const float* __restrict__ b1,
    const float* __restrict__ W2, float* __restrict__ ok)
{
    __shared__ float a[H];
    __shared__ float red[H];
    int b = blockIdx.x, g = b >> 2, k = b & 3;
    int c = threadIdx.x;
    a[c] = aggr[g*H + c];
    __syncthreads();
    float acc = b1[k*H + c];
    const float* wp = W1 + (size_t)k*H*H + c;
#pragma unroll 8
    for (int q=0; q<H; q++) acc += a[q] * wp[(size_t)q*H];
    red[c] = fmaxf(acc, 0.f) * W2[k*H + c];
    __syncthreads();
    for (int sd=64; sd>0; sd>>=1){
        if (c < sd) red[c] += red[c+sd];
        __syncthreads();
    }
    if (c == 0) ok[b] = red[0];
}

// ---------------- evidential epilogue ----------------
__global__ void k_evid(const float* __restrict__ ok, const float* __restrict__ b2,
                       float* __restrict__ out)
{
    int g = blockIdx.x*256 + threadIdx.x;
    if (g >= NG) return;
    float o0 = ok[g*4+0] + b2[0];
    float o1 = ok[g*4+1] + b2[1];
    float o2 = ok[g*4+2] + b2[2];
    float o3 = ok[g*4+3] + b2[3];
    float alpha = fmaxf(softplusf(o0) + 1.f, 1.f + 1e-4f);
    float beta  = softplusf(o1);
    float nu    = softplusf(o2);
    float am1   = alpha - 1.f;
    float aleat = beta / am1;
    float epis  = beta / (am1 * nu);
    out[0*NG+g] = o3;
    out[1*NG+g] = aleat;
    out[2*NG+g] = epis;
    out[3*NG+g] = nu;
    out[4*NG+g] = alpha;
    out[5*NG+g] = beta;
}

extern "C" void kernel_launch(void* const* d_in, const int* in_sizes, int n_in,
                              void* d_out, int out_size, void* d_ws, size_t ws_size,
                              hipStream_t stream)
{
    const int*   z     = (const int*)d_in[0];
    const float* pos   = (const float*)d_in[1];
    const int*   batch = (const int*)d_in[2];
    const int*   eidx  = (const int*)d_in[3];
    const float* emb   = (const float*)d_in[4];
    const float* Wp    = (const float*)d_in[5];
    const float* bp    = (const float*)d_in[6];
    const float* Wc    = (const float*)d_in[7];
    const float* bc    = (const float*)d_in[8];
    const float* gW1   = (const float*)d_in[9];
    const float* gb1   = (const float*)d_in[10];
    const float* gW2   = (const float*)d_in[11];
    const float* gb2   = (const float*)d_in[12];
    const float* hW1   = (const float*)d_in[13];
    const float* hb1   = (const float*)d_in[14];
    const float* hW2   = (const float*)d_in[15];
    const float* hb2   = (const float*)d_in[16];
    float* out = (float*)d_out;

    bool ok_sizes = (n_in == 17)
        && in_sizes[0] == NN && in_sizes[1] == NN*3 && in_sizes[2] == NN
        && in_sizes[3] == 2*NE && in_sizes[4] == 100*H
        && in_sizes[7] == 2*H*H && in_sizes[9] == 4*H*H
        && in_sizes[13] == 4*H*H && in_sizes[16] == 4;
    if (!ok_sizes){ k_sentinel<<<12, 256, 0, stream>>>(out, 600000.0f); return; }

    // double-buffered feature arrays (A = final output buffer for pooling)
    const size_t OFF_XA   = 256;        // 25,600,000
    const size_t OFF_XB_  = 25600256;   // x buffer B: 25,600,000 (also hosts CSR temps pre-loop)
    const size_t OFF_BA   = 51200256;   // xb (bf16) A: 12,800,000
    const size_t OFF_AGGR = 64000256;
    const size_t OFF_IPTR = 64262400;
    const size_t OFF_ESRC = 64662464;   // 3,200,000
    const size_t OFF_WF   = 67863296;   // 524,288
    const size_t OFF_WCF  = 68387584;   // 131,072
    const size_t OFF_OK   = 68518656;   // 8,192
    const size_t OFF_BB_B = 68526848;   // xb (bf16) B: 12,800,000
    const size_t REQ      = 81326848;
    if (ws_size < REQ){ k_sentinel<<<12, 256, 0, stream>>>(out, 500000.0f); return; }

    // CSR temps inside x-buffer-B region (dead until layer 0 writes it)
    const size_t OFF_TMP2 = OFF_XB_;            // NE*4 = 3.2 MB
    const size_t OFF_CNT  = OFF_XB_ + 3200000;  // 200,704
    const size_t OFF_SOFF = OFF_XB_ + 3401216;  // 200,704
    const size_t OFF_TOT  = OFF_XB_ + 3602176;  // 784
    const size_t OFF_BBB  = OFF_XB_ + 3603200;  // 788

    char* ws = (char*)d_ws;
    float*    xA   = (float*)(ws + OFF_XA);
    float*    xB   = (float*)(ws + OFF_XB_);
    unsigned* bA   = (unsigned*)(ws + OFF_BA);
    unsigned* bB   = (unsigned*)(ws + OFF_BB_B);
    float*    aggr = (float*)(ws + OFF_AGGR);
    int*      iptr = (int*)(ws + OFF_IPTR);
    int*      esrc = (int*)(ws + OFF_ESRC);
    uint4*    wf   = (uint4*)(ws + OFF_WF);
    uint4*    wcf  = (uint4*)(ws + OFF_WCF);
    float*    okb  = (float*)(ws + OFF_OK);
    unsigned* tmp  = (unsigned*)(ws + OFF_TMP2);
    int*      cnt  = (int*)(ws + OFF_CNT);
    int*      soff = (int*)(ws + OFF_SOFF);
    int*      tot  = (int*)(ws + OFF_TOT);
    int*      bb   = (int*)(ws + OFF_BBB);

    k_wsplit_embed<<<64, 64, 0, stream>>>(Wc, wcf);
    k_embed_mfma<<<(NN+63)/64, 256, 0, stream>>>(z, pos, emb, Wp, bp, bc, wcf, xA, bA);
    k_wsplit<<<256, 64, 0, stream>>>(gW1, gW2, wf);

    // contention-free CSR build (packed dword tmp)
    k_hist <<<256, 256, 0, stream>>>(eidx, cnt);
    k_btot <<<NBK, 256, 0, stream>>>(cnt, tot);
    k_bscan<<<1,   256, 0, stream>>>(tot, bb);
    k_soff <<<NBK, 256, 0, stream>>>(cnt, bb, soff);
    k_part <<<256, 256, 0, stream>>>(eidx, soff, tmp);
    k_final<<<NBK, 256, 0, stream>>>(bb, tmp, esrc, iptr);

    // fused GIN layers, double-buffered: A->B->A->B->A
    float*    xi = xA;  unsigned* bi = bA;
    float*    xo = xB;  unsigned* bo = bB;
    for (int l=0;l<4;l++){
        k_gin_fused<<<(NN+31)/32, 256, 0, stream>>>(xi, bi, iptr, esrc,
            gb1 + (size_t)l*H, gb2 + (size_t)l*H, wf, xo, bo, l, (l<3)?1:0);
        float* xt = xi; xi = xo; xo = xt;
        unsigned* bt = bi; bi = bo; bo = bt;
    }
    // after 4 layers the final features are back in xA

    k_pool<<<NG, 128, 0, stream>>>(xA, batch, aggr);
    k_head_dot<<<NG*4, 128, 0, stream>>>(aggr, hW1, hb1, hW2, okb);
    k_evid<<<(NG+255)/256, 256, 0, stream>>>(okb, hb2, out);
}

// Round 17
// 354.955 us; speedup vs baseline: 2.0324x; 1.1166x over previous
//
#include <hip/hip_runtime.h>
#include <stdint.h>

#define NN 50000
#define NE 800000
#define NG 512
#define H  128
#define NBK 196      // ceil(NN/256) node buckets
#define EPB 3125     // edges per partition block (NE/256)

typedef __attribute__((ext_vector_type(8))) short short8;
typedef __attribute__((ext_vector_type(16))) float f32x16;

union U4S8 { uint4 u; short8 s; };

__device__ __forceinline__ float softplusf(float x){
    return fmaxf(x, 0.f) + log1pf(expf(-fabsf(x)));
}

__device__ __forceinline__ unsigned rne_bf16_hi(float x){
    unsigned u = __float_as_uint(x);
    unsigned r = u + 0x7fffu + ((u >> 16) & 1u);
    return r & 0xffff0000u;
}

__device__ __forceinline__ void split_pack(float x0, float x1, unsigned &hi, unsigned &lo){
    unsigned h0 = rne_bf16_hi(x0), h1 = rne_bf16_hi(x1);
    hi = (h0 >> 16) | h1;
    float l0 = x0 - __uint_as_float(h0);
    float l1 = x1 - __uint_as_float(h1);
    unsigned g0 = rne_bf16_hi(l0), g1 = rne_bf16_hi(l1);
    lo = (g0 >> 16) | g1;
}

// ---------------- sentinel writer ----------------
__global__ void k_sentinel(float* out, float val){
    int i = blockIdx.x*256 + threadIdx.x;
    if (i < 6*NG) out[i] = val;
}

// ---------------- GIN W pre-split into MFMA B-fragment order ----------------
__global__ __launch_bounds__(64) void k_wsplit(const float* __restrict__ gW1,
    const float* __restrict__ gW2, uint4* __restrict__ wf)
{
    int bid = blockIdx.x, lane = threadIdx.x;
    int mat = bid >> 5, ntg = (bid >> 3) & 3, ks = bid & 7;
    int l = mat >> 1;
    const float* W = (mat & 1) ? (gW2 + (size_t)l*H*H) : (gW1 + (size_t)l*H*H);
    int n  = ntg*32 + (lane & 31);
    int kb = ks*16 + (lane >> 5)*8;
    unsigned hi[4], lo[4];
#pragma unroll
    for (int d=0; d<4; d++){
        float x0 = W[(size_t)(kb + 2*d    )*H + n];
        float x1 = W[(size_t)(kb + 2*d + 1)*H + n];
        split_pack(x0, x1, hi[d], lo[d]);
    }
    int bh = ((mat*2 + 0)*4 + ntg)*8 + ks;
    int bl = ((mat*2 + 1)*4 + ntg)*8 + ks;
    wf[bh*64 + lane] = make_uint4(hi[0],hi[1],hi[2],hi[3]);
    wf[bl*64 + lane] = make_uint4(lo[0],lo[1],lo[2],lo[3]);
}

// ---------------- W_comb (256x128) pre-split ----------------
__global__ __launch_bounds__(64) void k_wsplit_embed(const float* __restrict__ Wc,
    uint4* __restrict__ wcf)
{
    int bid = blockIdx.x, lane = threadIdx.x;
    int ntg = bid >> 4, ks = bid & 15;
    int n  = ntg*32 + (lane & 31);
    int kb = ks*16 + (lane >> 5)*8;
    unsigned hi[4], lo[4];
#pragma unroll
    for (int d=0; d<4; d++){
        float x0 = Wc[(size_t)(kb + 2*d    )*H + n];
        float x1 = Wc[(size_t)(kb + 2*d + 1)*H + n];
        split_pack(x0, x1, hi[d], lo[d]);
    }
    wcf[((0*4 + ntg)*16 + ks)*64 + lane] = make_uint4(hi[0],hi[1],hi[2],hi[3]);
    wcf[((1*4 + ntg)*16 + ks)*64 + lane] = make_uint4(lo[0],lo[1],lo[2],lo[3]);
}

// ---------------- initial embedding via MFMA (writes xA + xbA) ----------------
__global__ __launch_bounds__(256) void k_embed_mfma(const int* __restrict__ z,
    const float* __restrict__ pos, const float* __restrict__ emb,
    const float* __restrict__ Wp, const float* __restrict__ bp,
    const float* __restrict__ bc, const uint4* __restrict__ wcf,
    float* __restrict__ xout, unsigned* __restrict__ xbu)
{
    __shared__ unsigned short AhiF[2*8*64*8];
    __shared__ unsigned short AloF[2*8*64*8];
    const int t = threadIdx.x, lane = t & 63, w = t >> 6;
    const int rt = w & 1, cp = w >> 1;
    const int mb = blockIdx.x * 64;
    const int c31 = lane & 31;
    const int q = lane >> 5;

    const int r = t >> 2, c4 = t & 3;
    const int gr = mb + r;
    const int gre = (gr < NN) ? gr : (NN-1);
    const int zr = z[gre];
    const float p0 = pos[gre*3+0], p1 = pos[gre*3+1], p2 = pos[gre*3+2];
    const int rt_s = r >> 5, r31s = r & 31;

    f32x16 acc0, acc1;
#pragma unroll
    for (int i=0;i<16;i++){ acc0[i]=0.f; acc1[i]=0.f; }

#pragma unroll
    for (int kh2=0; kh2<2; kh2++){
        if (kh2) __syncthreads();
#pragma unroll
        for (int i=0;i<8;i++){
            int cl = c4*4 + i*16;
            float4 v;
            if (kh2 == 0){
                v = *(const float4*)(emb + (size_t)zr*H + cl);
            } else {
                float4 w0 = *(const float4*)(Wp + cl);
                float4 w1 = *(const float4*)(Wp + H + cl);
                float4 w2 = *(const float4*)(Wp + 2*H + cl);
                float4 bb = *(const float4*)(bp + cl);
                v.x = p0*w0.x + p1*w1.x + p2*w2.x + bb.x;
                v.y = p0*w0.y + p1*w1.y + p2*w2.y + bb.y;
                v.z = p0*w0.z + p1*w1.z + p2*w2.z + bb.z;
                v.w = p0*w0.w + p1*w1.w + p2*w2.w + bb.w;
            }
            unsigned h0,l0,h1,l1;
            split_pack(v.x, v.y, h0, l0);
            split_pack(v.z, v.w, h1, l1);
            int idx = ((rt_s*8 + (cl>>4))*64 + ((cl>>3)&1)*32 + r31s)*8 + (cl & 7);
            *(uint2*)&AhiF[idx] = make_uint2(h0, h1);
            *(uint2*)&AloF[idx] = make_uint2(l0, l1);
        }
        __syncthreads();
#pragma unroll
        for (int ks=0; ks<8; ks++){
            int ksg = kh2*8 + ks;
            U4S8 ah, al, bh0, bl0, bh1, bl1;
            ah.u  = *(const uint4*)&AhiF[((rt*8+ks)*64 + lane)*8];
            al.u  = *(const uint4*)&AloF[((rt*8+ks)*64 + lane)*8];
            bh0.u = wcf[((0*4 + 2*cp+0)*16 + ksg)*64 + lane];
            bl0.u = wcf[((1*4 + 2*cp+0)*16 + ksg)*64 + lane];
            bh1.u = wcf[((0*4 + 2*cp+1)*16 + ksg)*64 + lane];
            bl1.u = wcf[((1*4 + 2*cp+1)*16 + ksg)*64 + lane];
            acc0 = __builtin_amdgcn_mfma_f32_32x32x16_bf16(ah.s, bh0.s, acc0, 0,0,0);
            acc0 = __builtin_amdgcn_mfma_f32_32x32x16_bf16(ah.s, bl0.s, acc0, 0,0,0);
            acc0 = __builtin_amdgcn_mfma_f32_32x32x16_bf16(al.s, bh0.s, acc0, 0,0,0);
            acc1 = __builtin_amdgcn_mfma_f32_32x32x16_bf16(ah.s, bh1.s, acc1, 0,0,0);
            acc1 = __builtin_amdgcn_mfma_f32_32x32x16_bf16(ah.s, bl1.s, acc1, 0,0,0);
            acc1 = __builtin_amdgcn_mfma_f32_32x32x16_bf16(al.s, bh1.s, acc1, 0,0,0);
        }
    }

    const float bva = bc[64*cp + c31], bvb = bc[64*cp + 32 + c31];
#pragma unroll
    for (int reg=0; reg<16; reg++){
        int row = 32*rt + (reg & 3) + 8*(reg >> 2) + 4*q;
        int mm = mb + row;
        if (mm < NN){
            float v0 = fmaxf(acc0[reg] + bva, 0.f);
            float v1 = fmaxf(acc1[reg] + bvb, 0.f);
            xout[(size_t)mm*H + 64*cp      + c31] = v0;
            xout[(size_t)mm*H + 64*cp + 32 + c31] = v1;
            float pa = __shfl_xor(v0, 1);
            float pb = __shfl_xor(v1, 1);
            if (!(lane & 1)){
                unsigned u0 = (rne_bf16_hi(v0) >> 16) | (rne_bf16_hi(pa) & 0xffff0000u);
                unsigned u1 = (rne_bf16_hi(v1) >> 16) | (rne_bf16_hi(pb) & 0xffff0000u);
                xbu[(size_t)mm*64 + 32*cp      + (c31>>1)] = u0;
                xbu[(size_t)mm*64 + 32*cp + 16 + (c31>>1)] = u1;
            }
        }
    }
}

// ---------------- FUSED GIN layer v2: quarter-wave gather + 2-phase MFMA MLP ----------------
// Tile 32 rows x 128 cols; 256 thr = 4 waves.
// Gather: lane c=l&15 owns cols 8c..8c+7 of a row; per edge one uint4 (8 bf16 cols).
// Wave w, pass p (2 passes): rows m = w*8 + p*4 + (l>>4).  4 independent edge streams/wave.
// Frag store: lane's 8 cols == exactly one A-frag element run; XOR swizzle m' = m ^ ks
// spreads banks (8 accesses/bank, optimal).  MFMA reads use the same swizzle.
__global__ __launch_bounds__(256) void k_gin_fused(
    const float* __restrict__ xin, const unsigned* __restrict__ xbin,
    const int* __restrict__ iptr, const int* __restrict__ esrc,
    const float* __restrict__ b1, const float* __restrict__ b2,
    const uint4* __restrict__ wf,
    float* __restrict__ xout, unsigned* __restrict__ xbout,
    int l, int relu2)
{
    __shared__ unsigned short AhiF[8*64*8];   // 8 KB
    __shared__ unsigned short AloF[8*64*8];   // 8 KB
    const int t = threadIdx.x, lane = t & 63, w = t >> 6;
    const int mb = blockIdx.x * 32;
    const int c31 = lane & 31;
    const int q = lane >> 5;
    const int c  = lane & 15;       // col chunk (8 cols)
    const int jr = lane >> 4;       // row-within-pass (0..3)
    const int ksw = c >> 1, qw = c & 1;   // frag coords of this chunk

    const uint4* __restrict__ xbp = (const uint4*)xbin;   // row stride 16 uint4

#define ACC8(U)  { unsigned _u; \
    _u=(U).x; a0 += __uint_as_float(_u<<16); a1 += __uint_as_float(_u&0xffff0000u); \
    _u=(U).y; a2 += __uint_as_float(_u<<16); a3 += __uint_as_float(_u&0xffff0000u); \
    _u=(U).z; a4 += __uint_as_float(_u<<16); a5 += __uint_as_float(_u&0xffff0000u); \
    _u=(U).w; a6 += __uint_as_float(_u<<16); a7 += __uint_as_float(_u&0xffff0000u); }

#pragma unroll
    for (int p=0; p<2; p++){
        int m  = w*8 + p*4 + jr;          // row within tile
        int mm = mb + m;
        int mme = (mm < NN) ? mm : (NN-1);
        int s = iptr[mme], e = iptr[mme+1];
        s = max(0, min(s, NE));
        e = max(s, min(e, NE));
        // self term (fp32)
        const float4* xrow = (const float4*)(xin + (size_t)mme*H + c*8);
        float4 s0 = xrow[0], s1 = xrow[1];
        float a0=s0.x, a1=s0.y, a2=s0.z, a3=s0.w, a4=s1.x, a5=s1.y, a6=s1.z, a7=s1.w;
        int j = s;
        for (; j+4 <= e; j += 4){
            int i0 = esrc[j+0], i1 = esrc[j+1], i2 = esrc[j+2], i3 = esrc[j+3];
            uint4 u0 = xbp[(size_t)i0*16 + c];
            uint4 u1 = xbp[(size_t)i1*16 + c];
            uint4 u2 = xbp[(size_t)i2*16 + c];
            uint4 u3 = xbp[(size_t)i3*16 + c];
            ACC8(u0); ACC8(u1); ACC8(u2); ACC8(u3);
        }
        for (; j < e; j++){
            uint4 u = xbp[(size_t)esrc[j]*16 + c];
            ACC8(u);
        }
        // split to bf16 hi/lo and store one uint4 per array (swizzled frag order)
        unsigned hi4x, hi4y, hi4z, hi4w, lo4x, lo4y, lo4z, lo4w;
        split_pack(a0, a1, hi4x, lo4x);
        split_pack(a2, a3, hi4y, lo4y);
        split_pack(a4, a5, hi4z, lo4z);
        split_pack(a6, a7, hi4w, lo4w);
        int idx = (ksw*64 + qw*32 + (m ^ ksw))*8;
        *(uint4*)&AhiF[idx] = make_uint4(hi4x, hi4y, hi4z, hi4w);
        *(uint4*)&AloF[idx] = make_uint4(lo4x, lo4y, lo4z, lo4w);
    }
#undef ACC8
    __syncthreads();

    const float bv1 = b1[w*32 + c31];
    const float bv2 = b2[w*32 + c31];
    const int mat1 = l*2, mat2 = l*2 + 1;

    f32x16 acc;
#pragma unroll
    for (int i=0;i<16;i++) acc[i] = 0.f;

    // ---- phase 1: T = relu(h@W1 + b1), cols [w*32, w*32+32) ----
#pragma unroll
    for (int ks=0; ks<8; ks++){
        U4S8 ah, al, bh, bl;
        ah.u = *(const uint4*)&AhiF[(ks*64 + q*32 + (c31 ^ ks))*8];
        al.u = *(const uint4*)&AloF[(ks*64 + q*32 + (c31 ^ ks))*8];
        bh.u = wf[(((mat1*2+0)*4 + w)*8 + ks)*64 + lane];
        bl.u = wf[(((mat1*2+1)*4 + w)*8 + ks)*64 + lane];
        acc = __builtin_amdgcn_mfma_f32_32x32x16_bf16(ah.s, bh.s, acc, 0,0,0);
        acc = __builtin_amdgcn_mfma_f32_32x32x16_bf16(ah.s, bl.s, acc, 0,0,0);
        acc = __builtin_amdgcn_mfma_f32_32x32x16_bf16(al.s, bh.s, acc, 0,0,0);
    }

    // ---- T -> LDS frag-order (bf16 hi/lo), swizzled ----
    __syncthreads();
    {
        int k   = w*32 + c31;
        int kst = k >> 4, qt = (k >> 3) & 1, jj = k & 7;
#pragma unroll
        for (int reg=0; reg<16; reg++){
            int row = (reg & 3) + 8*(reg >> 2) + 4*q;
            float v = fmaxf(acc[reg] + bv1, 0.f);
            int idx = (kst*64 + qt*32 + (row ^ kst))*8 + jj;
            unsigned hb = rne_bf16_hi(v);
            AhiF[idx] = (unsigned short)(hb >> 16);
            AloF[idx] = (unsigned short)(rne_bf16_hi(v - __uint_as_float(hb)) >> 16);
        }
    }
    __syncthreads();

    // ---- phase 2: Y = T@W2 + b2 ----
#pragma unroll
    for (int i=0;i<16;i++) acc[i] = 0.f;
#pragma unroll
    for (int ks=0; ks<8; ks++){
        U4S8 ah, al, bh, bl;
        ah.u = *(const uint4*)&AhiF[(ks*64 + q*32 + (c31 ^ ks))*8];
        al.u = *(const uint4*)&AloF[(ks*64 + q*32 + (c31 ^ ks))*8];
        bh.u = wf[(((mat2*2+0)*4 + w)*8 + ks)*64 + lane];
        bl.u = wf[(((mat2*2+1)*4 + w)*8 + ks)*64 + lane];
        acc = __builtin_amdgcn_mfma_f32_32x32x16_bf16(ah.s, bh.s, acc, 0,0,0);
        acc = __builtin_amdgcn_mfma_f32_32x32x16_bf16(ah.s, bl.s, acc, 0,0,0);
        acc = __builtin_amdgcn_mfma_f32_32x32x16_bf16(al.s, bh.s, acc, 0,0,0);
    }

    // ---- epilogue: fp32 + bf16 copy to global (double-buffered out) ----
#pragma unroll
    for (int reg=0; reg<16; reg++){
        int row = (reg & 3) + 8*(reg >> 2) + 4*q;
        int mm = mb + row;
        if (mm < NN){
            float v = acc[reg] + bv2;
            if (relu2) v = fmaxf(v, 0.f);
            xout[(size_t)mm*H + w*32 + c31] = v;
            float p = __shfl_xor(v, 1);
            if (!(lane & 1)){
                unsigned u = (rne_bf16_hi(v) >> 16) | (rne_bf16_hi(p) & 0xffff0000u);
                xbout[(size_t)mm*64 + w*16 + (c31>>1)] = u;
            }
        }
    }
}

// ================ contention-free CSR build (two-level radix partition) ================
__global__ __launch_bounds__(256) void k_hist(const int* __restrict__ ei, int* __restrict__ cnt){
    __shared__ int hist[256];
    int blk = blockIdx.x, t = threadIdx.x;
    hist[t] = 0;
    __syncthreads();
    int e0 = blk*EPB, e1 = min(e0+EPB, NE);
    for (int e = e0+t; e < e1; e += 256){
        int d = ei[NE+e];
        if ((unsigned)d < NN) atomicAdd(&hist[d>>8], 1);
    }
    __syncthreads();
    if (t < NBK) cnt[t*256 + blk] = hist[t];
}

__global__ __launch_bounds__(256) void k_btot(const int* __restrict__ cnt, int* __restrict__ tot){
    __shared__ int s[256];
    int k = blockIdx.x, t = threadIdx.x;
    s[t] = cnt[k*256 + t];
    __syncthreads();
    for (int sd=128; sd>0; sd>>=1){
        if (t < sd) s[t] += s[t+sd];
        __syncthreads();
    }
    if (t == 0) tot[k] = s[0];
}

__global__ __launch_bounds__(256) void k_bscan(const int* __restrict__ tot, int* __restrict__ bb){
    __shared__ int sc[256];
    int t = threadIdx.x;
    int v = (t < NBK) ? tot[t] : 0;
    sc[t] = v;
    for (int off=1; off<256; off<<=1){
        __syncthreads();
        int tv = (t >= off) ? sc[t-off] : 0;
        __syncthreads();
        sc[t] += tv;
    }
    __syncthreads();
    if (t == 0) bb[0] = 0;
    if (t < NBK) bb[t+1] = sc[t];
}

__global__ __launch_bounds__(256) void k_soff(const int* __restrict__ cnt,
    const int* __restrict__ bb, int* __restrict__ soff)
{
    __shared__ int sc[256];
    int k = blockIdx.x, t = threadIdx.x;
    int v = cnt[k*256 + t];
    sc[t] = v;
    for (int off=1; off<256; off<<=1){
        __syncthreads();
        int tv = (t >= off) ? sc[t-off] : 0;
        __syncthreads();
        sc[t] += tv;
    }
    __syncthreads();
    soff[k*256 + t] = bb[k] + sc[t] - v;
}

__global__ __launch_bounds__(256) void k_part(const int* __restrict__ ei,
    const int* __restrict__ soff, unsigned* __restrict__ tmp)
{
    __shared__ unsigned edgeL[EPB];
    __shared__ int sc[256], startv[256], curv[256];
    __shared__ int tots;
    int blk = blockIdx.x, t = threadIdx.x;
    sc[t] = 0;
    __syncthreads();
    int e0 = blk*EPB, e1 = min(e0+EPB, NE);
    for (int e = e0+t; e < e1; e += 256){
        int d = ei[NE+e];
        if ((unsigned)d < NN) atomicAdd(&sc[d>>8], 1);
    }
    __syncthreads();
    int v = sc[t];
    for (int off=1; off<256; off<<=1){
        __syncthreads();
        int tv = (t >= off) ? sc[t-off] : 0;
        __syncthreads();
        sc[t] += tv;
    }
    __syncthreads();
    startv[t] = sc[t] - v;
    curv[t]   = sc[t] - v;
    if (t == 255) tots = sc[255];
    __syncthreads();
    for (int e = e0+t; e < e1; e += 256){
        int d = ei[NE+e];
        if ((unsigned)d < NN){
            unsigned u = (unsigned)ei[e] | ((unsigned)d << 16);
            int p = atomicAdd(&curv[d>>8], 1);
            edgeL[p] = u;
        }
    }
    __syncthreads();
    int nTot = tots;
    for (int i = t; i < nTot; i += 256){
        unsigned u = edgeL[i];
        int b = u >> 24;   // dst>>8
        int g = soff[b*256 + blk] + (i - startv[b]);
        tmp[g] = u;
    }
}

__global__ __launch_bounds__(256) void k_final(const int* __restrict__ bb,
    const unsigned* __restrict__ tmp, int* __restrict__ esrc, int* __restrict__ iptr)
{
    __shared__ int cntN[256], sc[256], curN[256];
    int k = blockIdx.x, t = threadIdx.x;
    int n0 = k*256;
    int nn = min(256, NN - n0);
    int base = bb[k], end = bb[k+1];
    cntN[t] = 0;
    __syncthreads();
    for (int i = base+t; i < end; i += 256){
        int d = (int)(tmp[i] >> 16) - n0;
        if ((unsigned)d < 256u) atomicAdd(&cntN[d], 1);
    }
    __syncthreads();
    int v = cntN[t];
    sc[t] = v;
    for (int off=1; off<256; off<<=1){
        __syncthreads();
        int tv = (t >= off) ? sc[t-off] : 0;
        __syncthreads();
        sc[t] += tv;
    }
    __syncthreads();
    int excl = sc[t] - v;
    curN[t] = excl;
    if (t < nn) iptr[n0 + t] = base + excl;
    if (k == NBK-1 && t == 0) iptr[NN] = end;
    __syncthreads();
    for (int i = base+t; i < end; i += 256){
        unsigned u = tmp[i];
        int d = (int)(u >> 16) - n0;
        if ((unsigned)d < 256u){
            int p = atomicAdd(&curN[d], 1);
            esrc[base + p] = (int)(u & 0xffffu);
        }
    }
}

// ---------------- per-graph sum pooling ----------------
__global__ __launch_bounds__(128) void k_pool(const float* __restrict__ x,
    const int* __restrict__ batch, float* __restrict__ aggr)
{
    int g = blockIdx.x, c = threadIdx.x;
    int lo=0, hi=NN;
    while (lo<hi){ int mid=(lo+hi)>>1; if (batch[mid] < g) lo=mid+1; else hi=mid; }
    int s0 = lo;
    hi = NN;
    while (lo<hi){ int mid=(lo+hi)>>1; if (batch[mid] < g+1) lo=mid+1; else hi=mid; }
    int e0 = lo;
    float a0=0.f, a1=0.f, a2=0.f, a3=0.f;
    int i = s0;
    for (; i+4 <= e0; i += 4){
        a0 += x[(size_t)(i+0)*H + c];
        a1 += x[(size_t)(i+1)*H + c];
        a2 += x[(size_t)(i+2)*H + c];
        a3 += x[(size_t)(i+3)*H + c];
    }
    for (; i < e0; i++) a0 += x[(size_t)i*H + c];
    aggr[g*H + c] = (a0+a1) + (a2+a3);
}

// ---------------- heads: per-(graph,head) dot kernel ----------------
__global__ __launch_bounds__(128) void k_head_dot(const float* __restrict__ aggr,
    const float* __restrict__ W1, const float* __restrict__ b1,
    const float* __restrict__ W2, float* __restrict__ ok)
{
    __shared__ float a[H];
    __shared__ float red[H];
    int b = blockIdx.x, g = b >> 2, k = b & 3;
    int c = threadIdx.x;
    a[c] = aggr[g*H + c];
    __syncthreads();
    float acc = b1[k*H + c];
    const float* wp = W1 + (size_t)k*H*H + c;
#pragma unroll 8
    for (int q=0; q<H; q++) acc += a[q] * wp[(size_t)q*H];
    red[c] = fmaxf(acc, 0.f) * W2[k*H + c];
    __syncthreads();
    for (int sd=64; sd>0; sd>>=1){
        if (c < sd) red[c] += red[c+sd];
        __syncthreads();
    }
    if (c == 0) ok[b] = red[0];
}

// ---------------- evidential epilogue ----------------
__global__ void k_evid(const float* __restrict__ ok, const float* __restrict__ b2,
                       float* __restrict__ out)
{
    int g = blockIdx.x*256 + threadIdx.x;
    if (g >= NG) return;
    float o0 = ok[g*4+0] + b2[0];
    float o1 = ok[g*4+1] + b2[1];
    float o2 = ok[g*4+2] + b2[2];
    float o3 = ok[g*4+3] + b2[3];
    float alpha = fmaxf(softplusf(o0) + 1.f, 1.f + 1e-4f);
    float beta  = softplusf(o1);
    float nu    = softplusf(o2);
    float am1   = alpha - 1.f;
    float aleat = beta / am1;
    float epis  = beta / (am1 * nu);
    out[0*NG+g] = o3;
    out[1*NG+g] = aleat;
    out[2*NG+g] = epis;
    out[3*NG+g] = nu;
    out[4*NG+g] = alpha;
    out[5*NG+g] = beta;
}

extern "C" void kernel_launch(void* const* d_in, const int* in_sizes, int n_in,
                              void* d_out, int out_size, void* d_ws, size_t ws_size,
                              hipStream_t stream)
{
    const int*   z     = (const int*)d_in[0];
    const float* pos   = (const float*)d_in[1];
    const int*   batch = (const int*)d_in[2];
    const int*   eidx  = (const int*)d_in[3];
    const float* emb   = (const float*)d_in[4];
    const float* Wp    = (const float*)d_in[5];
    const float* bp    = (const float*)d_in[6];
    const float* Wc    = (const float*)d_in[7];
    const float* bc    = (const float*)d_in[8];
    const float* gW1   = (const float*)d_in[9];
    const float* gb1   = (const float*)d_in[10];
    const float* gW2   = (const float*)d_in[11];
    const float* gb2   = (const float*)d_in[12];
    const float* hW1   = (const float*)d_in[13];
    const float* hb1   = (const float*)d_in[14];
    const float* hW2   = (const float*)d_in[15];
    const float* hb2   = (const float*)d_in[16];
    float* out = (float*)d_out;

    bool ok_sizes = (n_in == 17)
        && in_sizes[0] == NN && in_sizes[1] == NN*3 && in_sizes[2] == NN
        && in_sizes[3] == 2*NE && in_sizes[4] == 100*H
        && in_sizes[7] == 2*H*H && in_sizes[9] == 4*H*H
        && in_sizes[13] == 4*H*H && in_sizes[16] == 4;
    if (!ok_sizes){ k_sentinel<<<12, 256, 0, stream>>>(out, 600000.0f); return; }

    const size_t OFF_XA   = 256;
    const size_t OFF_XB_  = 25600256;
    const size_t OFF_BA   = 51200256;
    const size_t OFF_AGGR = 64000256;
    const size_t OFF_IPTR = 64262400;
    const size_t OFF_ESRC = 64662464;
    const size_t OFF_WF   = 67863296;
    const size_t OFF_WCF  = 68387584;
    const size_t OFF_OK   = 68518656;
    const size_t OFF_BB_B = 68526848;
    const size_t REQ      = 81326848;
    if (ws_size < REQ){ k_sentinel<<<12, 256, 0, stream>>>(out, 500000.0f); return; }

    const size_t OFF_TMP2 = OFF_XB_;
    const size_t OFF_CNT  = OFF_XB_ + 3200000;
    const size_t OFF_SOFF = OFF_XB_ + 3401216;
    const size_t OFF_TOT  = OFF_XB_ + 3602176;
    const size_t OFF_BBB  = OFF_XB_ + 3603200;

    char* ws = (char*)d_ws;
    float*    xA   = (float*)(ws + OFF_XA);
    float*    xB   = (float*)(ws + OFF_XB_);
    unsigned* bA   = (unsigned*)(ws + OFF_BA);
    unsigned* bB   = (unsigned*)(ws + OFF_BB_B);
    float*    aggr = (float*)(ws + OFF_AGGR);
    int*      iptr = (int*)(ws + OFF_IPTR);
    int*      esrc = (int*)(ws + OFF_ESRC);
    uint4*    wf   = (uint4*)(ws + OFF_WF);
    uint4*    wcf  = (uint4*)(ws + OFF_WCF);
    float*    okb  = (float*)(ws + OFF_OK);
    unsigned* tmp  = (unsigned*)(ws + OFF_TMP2);
    int*      cnt  = (int*)(ws + OFF_CNT);
    int*      soff = (int*)(ws + OFF_SOFF);
    int*      tot  = (int*)(ws + OFF_TOT);
    int*      bb   = (int*)(ws + OFF_BBB);

    k_wsplit_embed<<<64, 64, 0, stream>>>(Wc, wcf);
    k_embed_mfma<<<(NN+63)/64, 256, 0, stream>>>(z, pos, emb, Wp, bp, bc, wcf, xA, bA);
    k_wsplit<<<256, 64, 0, stream>>>(gW1, gW2, wf);

    k_hist <<<256, 256, 0, stream>>>(eidx, cnt);
    k_btot <<<NBK, 256, 0, stream>>>(cnt, tot);
    k_bscan<<<1,   256, 0, stream>>>(tot, bb);
    k_soff <<<NBK, 256, 0, stream>>>(cnt, bb, soff);
    k_part <<<256, 256, 0, stream>>>(eidx, soff, tmp);
    k_final<<<NBK, 256, 0, stream>>>(bb, tmp, esrc, iptr);

    float*    xi = xA;  unsigned* bi = bA;
    float*    xo = xB;  unsigned* bo = bB;
    for (int l=0;l<4;l++){
        k_gin_fused<<<(NN+31)/32, 256, 0, stream>>>(xi, bi, iptr, esrc,
            gb1 + (size_t)l*H, gb2 + (size_t)l*H, wf, xo, bo, l, (l<3)?1:0);
        float* xt = xi; xi = xo; xo = xt;
        unsigned* bt = bi; bi = bo; bo = bt;
    }

    k_pool<<<NG, 128, 0, stream>>>(xA, batch, aggr);
    k_head_dot<<<NG*4, 128, 0, stream>>>(aggr, hW1, hb1, hW2, okb);
    k_evid<<<(NG+255)/256, 256, 0, stream>>>(okb, hb2, out);
}

// Round 18
// 341.424 us; speedup vs baseline: 2.1130x; 1.0396x over previous
//
#include <hip/hip_runtime.h>
#include <stdint.h>

#define NN 50000
#define NE 800000
#define NG 512
#define H  128
#define NBK 196      // ceil(NN/256) node buckets
#define EPB 3125     // edges per partition block (NE/256)

typedef __attribute__((ext_vector_type(8))) short short8;
typedef __attribute__((ext_vector_type(16))) float f32x16;

union U4S8 { uint4 u; short8 s; };

__device__ __forceinline__ float softplusf(float x){
    return fmaxf(x, 0.f) + log1pf(expf(-fabsf(x)));
}

__device__ __forceinline__ unsigned rne_bf16_hi(float x){
    unsigned u = __float_as_uint(x);
    unsigned r = u + 0x7fffu + ((u >> 16) & 1u);
    return r & 0xffff0000u;
}

__device__ __forceinline__ void split_pack(float x0, float x1, unsigned &hi, unsigned &lo){
    unsigned h0 = rne_bf16_hi(x0), h1 = rne_bf16_hi(x1);
    hi = (h0 >> 16) | h1;
    float l0 = x0 - __uint_as_float(h0);
    float l1 = x1 - __uint_as_float(h1);
    unsigned g0 = rne_bf16_hi(l0), g1 = rne_bf16_hi(l1);
    lo = (g0 >> 16) | g1;
}

// ---------------- sentinel writer ----------------
__global__ void k_sentinel(float* out, float val){
    int i = blockIdx.x*256 + threadIdx.x;
    if (i < 6*NG) out[i] = val;
}

// ---------------- GIN W pre-split into MFMA B-fragment order ----------------
__global__ __launch_bounds__(64) void k_wsplit(const float* __restrict__ gW1,
    const float* __restrict__ gW2, uint4* __restrict__ wf)
{
    int bid = blockIdx.x, lane = threadIdx.x;
    int mat = bid >> 5, ntg = (bid >> 3) & 3, ks = bid & 7;
    int l = mat >> 1;
    const float* W = (mat & 1) ? (gW2 + (size_t)l*H*H) : (gW1 + (size_t)l*H*H);
    int n  = ntg*32 + (lane & 31);
    int kb = ks*16 + (lane >> 5)*8;
    unsigned hi[4], lo[4];
#pragma unroll
    for (int d=0; d<4; d++){
        float x0 = W[(size_t)(kb + 2*d    )*H + n];
        float x1 = W[(size_t)(kb + 2*d + 1)*H + n];
        split_pack(x0, x1, hi[d], lo[d]);
    }
    int bh = ((mat*2 + 0)*4 + ntg)*8 + ks;
    int bl = ((mat*2 + 1)*4 + ntg)*8 + ks;
    wf[bh*64 + lane] = make_uint4(hi[0],hi[1],hi[2],hi[3]);
    wf[bl*64 + lane] = make_uint4(lo[0],lo[1],lo[2],lo[3]);
}

// ---------------- W_comb (256x128) pre-split ----------------
__global__ __launch_bounds__(64) void k_wsplit_embed(const float* __restrict__ Wc,
    uint4* __restrict__ wcf)
{
    int bid = blockIdx.x, lane = threadIdx.x;
    int ntg = bid >> 4, ks = bid & 15;
    int n  = ntg*32 + (lane & 31);
    int kb = ks*16 + (lane >> 5)*8;
    unsigned hi[4], lo[4];
#pragma unroll
    for (int d=0; d<4; d++){
        float x0 = Wc[(size_t)(kb + 2*d    )*H + n];
        float x1 = Wc[(size_t)(kb + 2*d + 1)*H + n];
        split_pack(x0, x1, hi[d], lo[d]);
    }
    wcf[((0*4 + ntg)*16 + ks)*64 + lane] = make_uint4(hi[0],hi[1],hi[2],hi[3]);
    wcf[((1*4 + ntg)*16 + ks)*64 + lane] = make_uint4(lo[0],lo[1],lo[2],lo[3]);
}

// ---------------- initial embedding via MFMA (writes xb ONLY) ----------------
__global__ __launch_bounds__(256) void k_embed_mfma(const int* __restrict__ z,
    const float* __restrict__ pos, const float* __restrict__ emb,
    const float* __restrict__ Wp, const float* __restrict__ bp,
    const float* __restrict__ bc, const uint4* __restrict__ wcf,
    unsigned* __restrict__ xbu)
{
    __shared__ unsigned short AhiF[2*8*64*8];
    __shared__ unsigned short AloF[2*8*64*8];
    const int t = threadIdx.x, lane = t & 63, w = t >> 6;
    const int rt = w & 1, cp = w >> 1;
    const int mb = blockIdx.x * 64;
    const int c31 = lane & 31;
    const int q = lane >> 5;

    const int r = t >> 2, c4 = t & 3;
    const int gr = mb + r;
    const int gre = (gr < NN) ? gr : (NN-1);
    const int zr = z[gre];
    const float p0 = pos[gre*3+0], p1 = pos[gre*3+1], p2 = pos[gre*3+2];
    const int rt_s = r >> 5, r31s = r & 31;

    f32x16 acc0, acc1;
#pragma unroll
    for (int i=0;i<16;i++){ acc0[i]=0.f; acc1[i]=0.f; }

#pragma unroll
    for (int kh2=0; kh2<2; kh2++){
        if (kh2) __syncthreads();
#pragma unroll
        for (int i=0;i<8;i++){
            int cl = c4*4 + i*16;
            float4 v;
            if (kh2 == 0){
                v = *(const float4*)(emb + (size_t)zr*H + cl);
            } else {
                float4 w0 = *(const float4*)(Wp + cl);
                float4 w1 = *(const float4*)(Wp + H + cl);
                float4 w2 = *(const float4*)(Wp + 2*H + cl);
                float4 bb = *(const float4*)(bp + cl);
                v.x = p0*w0.x + p1*w1.x + p2*w2.x + bb.x;
                v.y = p0*w0.y + p1*w1.y + p2*w2.y + bb.y;
                v.z = p0*w0.z + p1*w1.z + p2*w2.z + bb.z;
                v.w = p0*w0.w + p1*w1.w + p2*w2.w + bb.w;
            }
            unsigned h0,l0,h1,l1;
            split_pack(v.x, v.y, h0, l0);
            split_pack(v.z, v.w, h1, l1);
            int idx = ((rt_s*8 + (cl>>4))*64 + ((cl>>3)&1)*32 + r31s)*8 + (cl & 7);
            *(uint2*)&AhiF[idx] = make_uint2(h0, h1);
            *(uint2*)&AloF[idx] = make_uint2(l0, l1);
        }
        __syncthreads();
#pragma unroll
        for (int ks=0; ks<8; ks++){
            int ksg = kh2*8 + ks;
            U4S8 ah, al, bh0, bl0, bh1, bl1;
            ah.u  = *(const uint4*)&AhiF[((rt*8+ks)*64 + lane)*8];
            al.u  = *(const uint4*)&AloF[((rt*8+ks)*64 + lane)*8];
            bh0.u = wcf[((0*4 + 2*cp+0)*16 + ksg)*64 + lane];
            bl0.u = wcf[((1*4 + 2*cp+0)*16 + ksg)*64 + lane];
            bh1.u = wcf[((0*4 + 2*cp+1)*16 + ksg)*64 + lane];
            bl1.u = wcf[((1*4 + 2*cp+1)*16 + ksg)*64 + lane];
            acc0 = __builtin_amdgcn_mfma_f32_32x32x16_bf16(ah.s, bh0.s, acc0, 0,0,0);
            acc0 = __builtin_amdgcn_mfma_f32_32x32x16_bf16(ah.s, bl0.s, acc0, 0,0,0);
            acc0 = __builtin_amdgcn_mfma_f32_32x32x16_bf16(al.s, bh0.s, acc0, 0,0,0);
            acc1 = __builtin_amdgcn_mfma_f32_32x32x16_bf16(ah.s, bh1.s, acc1, 0,0,0);
            acc1 = __builtin_amdgcn_mfma_f32_32x32x16_bf16(ah.s, bl1.s, acc1, 0,0,0);
            acc1 = __builtin_amdgcn_mfma_f32_32x32x16_bf16(al.s, bh1.s, acc1, 0,0,0);
        }
    }

    const float bva = bc[64*cp + c31], bvb = bc[64*cp + 32 + c31];
#pragma unroll
    for (int reg=0; reg<16; reg++){
        int row = 32*rt + (reg & 3) + 8*(reg >> 2) + 4*q;
        int mm = mb + row;
        if (mm < NN){
            float v0 = fmaxf(acc0[reg] + bva, 0.f);
            float v1 = fmaxf(acc1[reg] + bvb, 0.f);
            float pa = __shfl_xor(v0, 1);
            float pb = __shfl_xor(v1, 1);
            if (!(lane & 1)){
                unsigned u0 = (rne_bf16_hi(v0) >> 16) | (rne_bf16_hi(pa) & 0xffff0000u);
                unsigned u1 = (rne_bf16_hi(v1) >> 16) | (rne_bf16_hi(pb) & 0xffff0000u);
                xbu[(size_t)mm*64 + 32*cp      + (c31>>1)] = u0;
                xbu[(size_t)mm*64 + 32*cp + 16 + (c31>>1)] = u1;
            }
        }
    }
}

// ---------------- FUSED GIN layer v3: xb-only self-term, conditional outputs ----------------
// Tile 32 rows x 128 cols; 256 thr = 4 waves; quarter-wave gather (lane c=l&15 owns 8 cols).
// Self term + neighbors all from packed bf16 xb.  Layers 0-2 write xb only; layer 3 fp32 x only.
__global__ __launch_bounds__(256) void k_gin_fused(
    const unsigned* __restrict__ xbin,
    const int* __restrict__ iptr, const int* __restrict__ esrc,
    const float* __restrict__ b1, const float* __restrict__ b2,
    const uint4* __restrict__ wf,
    float* __restrict__ xout, unsigned* __restrict__ xbout,
    int l, int relu2, int wx, int wxb)
{
    __shared__ unsigned short AhiF[8*64*8];   // 8 KB
    __shared__ unsigned short AloF[8*64*8];   // 8 KB
    const int t = threadIdx.x, lane = t & 63, w = t >> 6;
    const int mb = blockIdx.x * 32;
    const int c31 = lane & 31;
    const int q = lane >> 5;
    const int c  = lane & 15;       // col chunk (8 cols)
    const int jr = lane >> 4;       // row-within-pass (0..3)
    const int ksw = c >> 1, qw = c & 1;

    const uint4* __restrict__ xbp = (const uint4*)xbin;   // row stride 16 uint4

#define ACC8(U)  { unsigned _u; \
    _u=(U).x; a0 += __uint_as_float(_u<<16); a1 += __uint_as_float(_u&0xffff0000u); \
    _u=(U).y; a2 += __uint_as_float(_u<<16); a3 += __uint_as_float(_u&0xffff0000u); \
    _u=(U).z; a4 += __uint_as_float(_u<<16); a5 += __uint_as_float(_u&0xffff0000u); \
    _u=(U).w; a6 += __uint_as_float(_u<<16); a7 += __uint_as_float(_u&0xffff0000u); }

#pragma unroll
    for (int p=0; p<2; p++){
        int m  = w*8 + p*4 + jr;
        int mm = mb + m;
        int mme = (mm < NN) ? mm : (NN-1);
        int s = iptr[mme], e = iptr[mme+1];
        s = max(0, min(s, NE));
        e = max(s, min(e, NE));
        // self term from xb (bf16)
        float a0=0.f,a1=0.f,a2=0.f,a3=0.f,a4=0.f,a5=0.f,a6=0.f,a7=0.f;
        {
            uint4 su = xbp[(size_t)mme*16 + c];
            ACC8(su);
        }
        int j = s;
        for (; j+4 <= e; j += 4){
            int i0 = esrc[j+0], i1 = esrc[j+1], i2 = esrc[j+2], i3 = esrc[j+3];
            uint4 u0 = xbp[(size_t)i0*16 + c];
            uint4 u1 = xbp[(size_t)i1*16 + c];
            uint4 u2 = xbp[(size_t)i2*16 + c];
            uint4 u3 = xbp[(size_t)i3*16 + c];
            ACC8(u0); ACC8(u1); ACC8(u2); ACC8(u3);
        }
        for (; j < e; j++){
            uint4 u = xbp[(size_t)esrc[j]*16 + c];
            ACC8(u);
        }
        unsigned hi4x, hi4y, hi4z, hi4w, lo4x, lo4y, lo4z, lo4w;
        split_pack(a0, a1, hi4x, lo4x);
        split_pack(a2, a3, hi4y, lo4y);
        split_pack(a4, a5, hi4z, lo4z);
        split_pack(a6, a7, hi4w, lo4w);
        int idx = (ksw*64 + qw*32 + (m ^ ksw))*8;
        *(uint4*)&AhiF[idx] = make_uint4(hi4x, hi4y, hi4z, hi4w);
        *(uint4*)&AloF[idx] = make_uint4(lo4x, lo4y, lo4z, lo4w);
    }
#undef ACC8
    __syncthreads();

    const float bv1 = b1[w*32 + c31];
    const float bv2 = b2[w*32 + c31];
    const int mat1 = l*2, mat2 = l*2 + 1;

    f32x16 acc;
#pragma unroll
    for (int i=0;i<16;i++) acc[i] = 0.f;

    // ---- phase 1: T = relu(h@W1 + b1) ----
#pragma unroll
    for (int ks=0; ks<8; ks++){
        U4S8 ah, al, bh, bl;
        ah.u = *(const uint4*)&AhiF[(ks*64 + q*32 + (c31 ^ ks))*8];
        al.u = *(const uint4*)&AloF[(ks*64 + q*32 + (c31 ^ ks))*8];
        bh.u = wf[(((mat1*2+0)*4 + w)*8 + ks)*64 + lane];
        bl.u = wf[(((mat1*2+1)*4 + w)*8 + ks)*64 + lane];
        acc = __builtin_amdgcn_mfma_f32_32x32x16_bf16(ah.s, bh.s, acc, 0,0,0);
        acc = __builtin_amdgcn_mfma_f32_32x32x16_bf16(ah.s, bl.s, acc, 0,0,0);
        acc = __builtin_amdgcn_mfma_f32_32x32x16_bf16(al.s, bh.s, acc, 0,0,0);
    }

    // ---- T -> LDS frag-order (bf16 hi/lo), swizzled ----
    __syncthreads();
    {
        int k   = w*32 + c31;
        int kst = k >> 4, qt = (k >> 3) & 1, jj = k & 7;
#pragma unroll
        for (int reg=0; reg<16; reg++){
            int row = (reg & 3) + 8*(reg >> 2) + 4*q;
            float v = fmaxf(acc[reg] + bv1, 0.f);
            int idx = (kst*64 + qt*32 + (row ^ kst))*8 + jj;
            unsigned hb = rne_bf16_hi(v);
            AhiF[idx] = (unsigned short)(hb >> 16);
            AloF[idx] = (unsigned short)(rne_bf16_hi(v - __uint_as_float(hb)) >> 16);
        }
    }
    __syncthreads();

    // ---- phase 2: Y = T@W2 + b2 ----
#pragma unroll
    for (int i=0;i<16;i++) acc[i] = 0.f;
#pragma unroll
    for (int ks=0; ks<8; ks++){
        U4S8 ah, al, bh, bl;
        ah.u = *(const uint4*)&AhiF[(ks*64 + q*32 + (c31 ^ ks))*8];
        al.u = *(const uint4*)&AloF[(ks*64 + q*32 + (c31 ^ ks))*8];
        bh.u = wf[(((mat2*2+0)*4 + w)*8 + ks)*64 + lane];
        bl.u = wf[(((mat2*2+1)*4 + w)*8 + ks)*64 + lane];
        acc = __builtin_amdgcn_mfma_f32_32x32x16_bf16(ah.s, bh.s, acc, 0,0,0);
        acc = __builtin_amdgcn_mfma_f32_32x32x16_bf16(ah.s, bl.s, acc, 0,0,0);
        acc = __builtin_amdgcn_mfma_f32_32x32x16_bf16(al.s, bh.s, acc, 0,0,0);
    }

    // ---- epilogue: conditional fp32 / bf16 outputs ----
#pragma unroll
    for (int reg=0; reg<16; reg++){
        int row = (reg & 3) + 8*(reg >> 2) + 4*q;
        int mm = mb + row;
        if (mm < NN){
            float v = acc[reg] + bv2;
            if (relu2) v = fmaxf(v, 0.f);
            if (wx) xout[(size_t)mm*H + w*32 + c31] = v;
            if (wxb){
                float p = __shfl_xor(v, 1);
                if (!(lane & 1)){
                    unsigned u = (rne_bf16_hi(v) >> 16) | (rne_bf16_hi(p) & 0xffff0000u);
                    xbout[(size_t)mm*64 + w*16 + (c31>>1)] = u;
                }
            }
        }
    }
}

// ================ contention-free CSR build (two-level radix partition) ================
__global__ __launch_bounds__(256) void k_hist(const int* __restrict__ ei, int* __restrict__ cnt){
    __shared__ int hist[256];
    int blk = blockIdx.x, t = threadIdx.x;
    hist[t] = 0;
    __syncthreads();
    int e0 = blk*EPB, e1 = min(e0+EPB, NE);
    for (int e = e0+t; e < e1; e += 256){
        int d = ei[NE+e];
        if ((unsigned)d < NN) atomicAdd(&hist[d>>8], 1);
    }
    __syncthreads();
    if (t < NBK) cnt[t*256 + blk] = hist[t];
}

__global__ __launch_bounds__(256) void k_btot(const int* __restrict__ cnt, int* __restrict__ tot){
    __shared__ int s[256];
    int k = blockIdx.x, t = threadIdx.x;
    s[t] = cnt[k*256 + t];
    __syncthreads();
    for (int sd=128; sd>0; sd>>=1){
        if (t < sd) s[t] += s[t+sd];
        __syncthreads();
    }
    if (t == 0) tot[k] = s[0];
}

__global__ __launch_bounds__(256) void k_bscan(const int* __restrict__ tot, int* __restrict__ bb){
    __shared__ int sc[256];
    int t = threadIdx.x;
    int v = (t < NBK) ? tot[t] : 0;
    sc[t] = v;
    for (int off=1; off<256; off<<=1){
        __syncthreads();
        int tv = (t >= off) ? sc[t-off] : 0;
        __syncthreads();
        sc[t] += tv;
    }
    __syncthreads();
    if (t == 0) bb[0] = 0;
    if (t < NBK) bb[t+1] = sc[t];
}

__global__ __launch_bounds__(256) void k_soff(const int* __restrict__ cnt,
    const int* __restrict__ bb, int* __restrict__ soff)
{
    __shared__ int sc[256];
    int k = blockIdx.x, t = threadIdx.x;
    int v = cnt[k*256 + t];
    sc[t] = v;
    for (int off=1; off<256; off<<=1){
        __syncthreads();
        int tv = (t >= off) ? sc[t-off] : 0;
        __syncthreads();
        sc[t] += tv;
    }
    __syncthreads();
    soff[k*256 + t] = bb[k] + sc[t] - v;
}

__global__ __launch_bounds__(256) void k_part(const int* __restrict__ ei,
    const int* __restrict__ soff, unsigned* __restrict__ tmp)
{
    __shared__ unsigned edgeL[EPB];
    __shared__ int sc[256], startv[256], curv[256];
    __shared__ int tots;
    int blk = blockIdx.x, t = threadIdx.x;
    sc[t] = 0;
    __syncthreads();
    int e0 = blk*EPB, e1 = min(e0+EPB, NE);
    for (int e = e0+t; e < e1; e += 256){
        int d = ei[NE+e];
        if ((unsigned)d < NN) atomicAdd(&sc[d>>8], 1);
    }
    __syncthreads();
    int v = sc[t];
    for (int off=1; off<256; off<<=1){
        __syncthreads();
        int tv = (t >= off) ? sc[t-off] : 0;
        __syncthreads();
        sc[t] += tv;
    }
    __syncthreads();
    startv[t] = sc[t] - v;
    curv[t]   = sc[t] - v;
    if (t == 255) tots = sc[255];
    __syncthreads();
    for (int e = e0+t; e < e1; e += 256){
        int d = ei[NE+e];
        if ((unsigned)d < NN){
            unsigned u = (unsigned)ei[e] | ((unsigned)d << 16);
            int p = atomicAdd(&curv[d>>8], 1);
            edgeL[p] = u;
        }
    }
    __syncthreads();
    int nTot = tots;
    for (int i = t; i < nTot; i += 256){
        unsigned u = edgeL[i];
        int b = u >> 24;
        int g = soff[b*256 + blk] + (i - startv[b]);
        tmp[g] = u;
    }
}

__global__ __launch_bounds__(256) void k_final(const int* __restrict__ bb,
    const unsigned* __restrict__ tmp, int* __restrict__ esrc, int* __restrict__ iptr)
{
    __shared__ int cntN[256], sc[256], curN[256];
    int k = blockIdx.x, t = threadIdx.x;
    int n0 = k*256;
    int nn = min(256, NN - n0);
    int base = bb[k], end = bb[k+1];
    cntN[t] = 0;
    __syncthreads();
    for (int i = base+t; i < end; i += 256){
        int d = (int)(tmp[i] >> 16) - n0;
        if ((unsigned)d < 256u) atomicAdd(&cntN[d], 1);
    }
    __syncthreads();
    int v = cntN[t];
    sc[t] = v;
    for (int off=1; off<256; off<<=1){
        __syncthreads();
        int tv = (t >= off) ? sc[t-off] : 0;
        __syncthreads();
        sc[t] += tv;
    }
    __syncthreads();
    int excl = sc[t] - v;
    curN[t] = excl;
    if (t < nn) iptr[n0 + t] = base + excl;
    if (k == NBK-1 && t == 0) iptr[NN] = end;
    __syncthreads();
    for (int i = base+t; i < end; i += 256){
        unsigned u = tmp[i];
        int d = (int)(u >> 16) - n0;
        if ((unsigned)d < 256u){
            int p = atomicAdd(&curN[d], 1);
            esrc[base + p] = (int)(u & 0xffffu);
        }
    }
}

// ---------------- per-graph sum pooling ----------------
__global__ __launch_bounds__(128) void k_pool(const float* __restrict__ x,
    const int* __restrict__ batch, float* __restrict__ aggr)
{
    int g = blockIdx.x, c = threadIdx.x;
    int lo=0, hi=NN;
    while (lo<hi){ int mid=(lo+hi)>>1; if (batch[mid] < g) lo=mid+1; else hi=mid; }
    int s0 = lo;
    hi = NN;
    while (lo<hi){ int mid=(lo+hi)>>1; if (batch[mid] < g+1) lo=mid+1; else hi=mid; }
    int e0 = lo;
    float a0=0.f, a1=0.f, a2=0.f, a3=0.f;
    int i = s0;
    for (; i+4 <= e0; i += 4){
        a0 += x[(size_t)(i+0)*H + c];
        a1 += x[(size_t)(i+1)*H + c];
        a2 += x[(size_t)(i+2)*H + c];
        a3 += x[(size_t)(i+3)*H + c];
    }
    for (; i < e0; i++) a0 += x[(size_t)i*H + c];
    aggr[g*H + c] = (a0+a1) + (a2+a3);
}

// ---------------- heads: per-(graph,head) dot kernel ----------------
__global__ __launch_bounds__(128) void k_head_dot(const float* __restrict__ aggr,
    const float* __restrict__ W1, const float* __restrict__ b1,
    const float* __restrict__ W2, float* __restrict__ ok)
{
    __shared__ float a[H];
    __shared__ float red[H];
    int b = blockIdx.x, g = b >> 2, k = b & 3;
    int c = threadIdx.x;
    a[c] = aggr[g*H + c];
    __syncthreads();
    float acc = b1[k*H + c];
    const float* wp = W1 + (size_t)k*H*H + c;
#pragma unroll 8
    for (int q=0; q<H; q++) acc += a[q] * wp[(size_t)q*H];
    red[c] = fmaxf(acc, 0.f) * W2[k*H + c];
    __syncthreads();
    for (int sd=64; sd>0; sd>>=1){
        if (c < sd) red[c] += red[c+sd];
        __syncthreads();
    }
    if (c == 0) ok[b] = red[0];
}

// ---------------- evidential epilogue ----------------
__global__ void k_evid(const float* __restrict__ ok, const float* __restrict__ b2,
                       float* __restrict__ out)
{
    int g = blockIdx.x*256 + threadIdx.x;
    if (g >= NG) return;
    float o0 = ok[g*4+0] + b2[0];
    float o1 = ok[g*4+1] + b2[1];
    float o2 = ok[g*4+2] + b2[2];
    float o3 = ok[g*4+3] + b2[3];
    float alpha = fmaxf(softplusf(o0) + 1.f, 1.f + 1e-4f);
    float beta  = softplusf(o1);
    float nu    = softplusf(o2);
    float am1   = alpha - 1.f;
    float aleat = beta / am1;
    float epis  = beta / (am1 * nu);
    out[0*NG+g] = o3;
    out[1*NG+g] = aleat;
    out[2*NG+g] = epis;
    out[3*NG+g] = nu;
    out[4*NG+g] = alpha;
    out[5*NG+g] = beta;
}

extern "C" void kernel_launch(void* const* d_in, const int* in_sizes, int n_in,
                              void* d_out, int out_size, void* d_ws, size_t ws_size,
                              hipStream_t stream)
{
    const int*   z     = (const int*)d_in[0];
    const float* pos   = (const float*)d_in[1];
    const int*   batch = (const int*)d_in[2];
    const int*   eidx  = (const int*)d_in[3];
    const float* emb   = (const float*)d_in[4];
    const float* Wp    = (const float*)d_in[5];
    const float* bp    = (const float*)d_in[6];
    const float* Wc    = (const float*)d_in[7];
    const float* bc    = (const float*)d_in[8];
    const float* gW1   = (const float*)d_in[9];
    const float* gb1   = (const float*)d_in[10];
    const float* gW2   = (const float*)d_in[11];
    const float* gb2   = (const float*)d_in[12];
    const float* hW1   = (const float*)d_in[13];
    const float* hb1   = (const float*)d_in[14];
    const float* hW2   = (const float*)d_in[15];
    const float* hb2   = (const float*)d_in[16];
    float* out = (float*)d_out;

    bool ok_sizes = (n_in == 17)
        && in_sizes[0] == NN && in_sizes[1] == NN*3 && in_sizes[2] == NN
        && in_sizes[3] == 2*NE && in_sizes[4] == 100*H
        && in_sizes[7] == 2*H*H && in_sizes[9] == 4*H*H
        && in_sizes[13] == 4*H*H && in_sizes[16] == 4;
    if (!ok_sizes){ k_sentinel<<<12, 256, 0, stream>>>(out, 600000.0f); return; }

    const size_t OFF_XA   = 256;        // fp32 x (written by layer 3 only): 25,600,000
    const size_t OFF_TMPR = 25600256;   // CSR temp region (dead after build): 25,600,000
    const size_t OFF_BA   = 51200256;   // xb A: 12,800,000
    const size_t OFF_AGGR = 64000256;
    const size_t OFF_IPTR = 64262400;
    const size_t OFF_ESRC = 64662464;
    const size_t OFF_WF   = 67863296;
    const size_t OFF_WCF  = 68387584;
    const size_t OFF_OK   = 68518656;
    const size_t OFF_BB_B = 68526848;   // xb B: 12,800,000
    const size_t REQ      = 81326848;
    if (ws_size < REQ){ k_sentinel<<<12, 256, 0, stream>>>(out, 500000.0f); return; }

    const size_t OFF_TMP2 = OFF_TMPR;
    const size_t OFF_CNT  = OFF_TMPR + 3200000;
    const size_t OFF_SOFF = OFF_TMPR + 3401216;
    const size_t OFF_TOT  = OFF_TMPR + 3602176;
    const size_t OFF_BBB  = OFF_TMPR + 3603200;

    char* ws = (char*)d_ws;
    float*    xA   = (float*)(ws + OFF_XA);
    unsigned* bA   = (unsigned*)(ws + OFF_BA);
    unsigned* bB   = (unsigned*)(ws + OFF_BB_B);
    float*    aggr = (float*)(ws + OFF_AGGR);
    int*      iptr = (int*)(ws + OFF_IPTR);
    int*      esrc = (int*)(ws + OFF_ESRC);
    uint4*    wf   = (uint4*)(ws + OFF_WF);
    uint4*    wcf  = (uint4*)(ws + OFF_WCF);
    float*    okb  = (float*)(ws + OFF_OK);
    unsigned* tmp  = (unsigned*)(ws + OFF_TMP2);
    int*      cnt  = (int*)(ws + OFF_CNT);
    int*      soff = (int*)(ws + OFF_SOFF);
    int*      tot  = (int*)(ws + OFF_TOT);
    int*      bb   = (int*)(ws + OFF_BBB);

    k_wsplit_embed<<<64, 64, 0, stream>>>(Wc, wcf);
    k_embed_mfma<<<(NN+63)/64, 256, 0, stream>>>(z, pos, emb, Wp, bp, bc, wcf, bA);
    k_wsplit<<<256, 64, 0, stream>>>(gW1, gW2, wf);

    k_hist <<<256, 256, 0, stream>>>(eidx, cnt);
    k_btot <<<NBK, 256, 0, stream>>>(cnt, tot);
    k_bscan<<<1,   256, 0, stream>>>(tot, bb);
    k_soff <<<NBK, 256, 0, stream>>>(cnt, bb, soff);
    k_part <<<256, 256, 0, stream>>>(eidx, soff, tmp);
    k_final<<<NBK, 256, 0, stream>>>(bb, tmp, esrc, iptr);

    // fused GIN layers on bf16 buffers: bA->bB->bA->bB, layer 3 emits fp32 xA
    unsigned* bi = bA;  unsigned* bo = bB;
    for (int l=0;l<4;l++){
        int wx  = (l == 3) ? 1 : 0;
        int wxb = (l <  3) ? 1 : 0;
        k_gin_fused<<<(NN+31)/32, 256, 0, stream>>>(bi, iptr, esrc,
            gb1 + (size_t)l*H, gb2 + (size_t)l*H, wf, xA, bo, l, (l<3)?1:0, wx, wxb);
        unsigned* bt = bi; bi = bo; bo = bt;
    }

    k_pool<<<NG, 128, 0, stream>>>(xA, batch, aggr);
    k_head_dot<<<NG*4, 128, 0, stream>>>(aggr, hW1, hb1, hW2, okb);
    k_evid<<<(NG+255)/256, 256, 0, stream>>>(okb, hb2, out);
}